// Round 9
// baseline (507.128 us; speedup 1.0000x reference)
//
#include <hip/hip_runtime.h>
#include <hip/hip_cooperative_groups.h>

namespace cg = cooperative_groups;

#define NEGINF (-1e30f)

// ---------------- problem constants ----------------
// b=4, c=64, h=w=5, q=75, u=100, N_WAY=5, K_SHOT=5
// M_s = 125 (per way), M_u = 2500, M_q = 25, M_tot = 2625
// ---------------- workspace layout (float units) ----------------
// Round-5 proven layout.
constexpr size_t OF_UNL  = 0;                              // [4][2500][64]
constexpr size_t OF_SUP  = OF_UNL  + (size_t)4*2500*64;    // [4][5][125][64]
constexpr size_t OF_SUPT = OF_SUP  + (size_t)4*5*125*64;   // [4][5][64][128]
constexpr size_t OF_QT   = OF_SUPT + (size_t)4*5*64*128;   // [300][28][64]
constexpr size_t OF_ROWV = OF_QT   + (size_t)300*28*64;    // [4][5][8ck][2500] f
constexpr size_t OF_ROWI = OF_ROWV + (size_t)4*5*8*2500;   // [4][5][8ck][2500] i
constexpr size_t OF_CVI  = OF_ROWI + (size_t)4*5*8*2500;   // [4][5][125][20][2]
constexpr size_t OF_CMP  = OF_CVI  + (size_t)4*5*125*20*2; // [4][5][2500] i
constexpr size_t OF_CNT  = OF_CMP  + (size_t)4*5*2500;     // [20] i
constexpr size_t OF_UNEAR= OF_CNT  + 20;                   // [4][2500] i
constexpr size_t OF_SNEAR= OF_UNEAR+ 10000;                // [4][625]  i
constexpr size_t OF_BV   = OF_SNEAR+ 2500;                 // [300][5][25] f
constexpr size_t OF_BP   = OF_BV   + 37500;                // [300][5][25] i
constexpr size_t OF_AMX  = OF_BP   + 37500;                // [300][3200] u8

typedef __attribute__((ext_vector_type(4)))  float f4s;
typedef __attribute__((ext_vector_type(16))) float f16s;

// ---- kb inner macros (verbatim round-5, bench-proven) ----
#define KB2(C) { \
    f16s s0, s1; \
    asm volatile("s_load_dwordx16 %0, %[b], %c[o0]\n\t" \
                 "s_load_dwordx16 %1, %[b], %c[o1]\n\t" \
                 "s_waitcnt lgkmcnt(0)" \
                 : "=s"(s0), "=s"(s1) \
                 : [b]"s"(sbp), [o0]"i"((C)*512), [o1]"i"((C)*512+512)); \
    float2 uv = *(const float2*)&uls[ml * 66 + (C)]; \
    acc[0]  = fmaf(uv.x, s0[0],  fmaf(uv.y, s1[0],  acc[0])); \
    acc[1]  = fmaf(uv.x, s0[1],  fmaf(uv.y, s1[1],  acc[1])); \
    acc[2]  = fmaf(uv.x, s0[2],  fmaf(uv.y, s1[2],  acc[2])); \
    acc[3]  = fmaf(uv.x, s0[3],  fmaf(uv.y, s1[3],  acc[3])); \
    acc[4]  = fmaf(uv.x, s0[4],  fmaf(uv.y, s1[4],  acc[4])); \
    acc[5]  = fmaf(uv.x, s0[5],  fmaf(uv.y, s1[5],  acc[5])); \
    acc[6]  = fmaf(uv.x, s0[6],  fmaf(uv.y, s1[6],  acc[6])); \
    acc[7]  = fmaf(uv.x, s0[7],  fmaf(uv.y, s1[7],  acc[7])); \
    acc[8]  = fmaf(uv.x, s0[8],  fmaf(uv.y, s1[8],  acc[8])); \
    acc[9]  = fmaf(uv.x, s0[9],  fmaf(uv.y, s1[9],  acc[9])); \
    acc[10] = fmaf(uv.x, s0[10], fmaf(uv.y, s1[10], acc[10])); \
    acc[11] = fmaf(uv.x, s0[11], fmaf(uv.y, s1[11], acc[11])); \
    acc[12] = fmaf(uv.x, s0[12], fmaf(uv.y, s1[12], acc[12])); \
    acc[13] = fmaf(uv.x, s0[13], fmaf(uv.y, s1[13], acc[13])); \
    acc[14] = fmaf(uv.x, s0[14], fmaf(uv.y, s1[14], acc[14])); \
    acc[15] = fmaf(uv.x, s0[15], fmaf(uv.y, s1[15], acc[15])); }
#define KB8(C) KB2(C) KB2((C)+2) KB2((C)+4) KB2((C)+6)

// ---- kc1 inner macros (verbatim round-5, bench-proven) ----
#define QLOAD(CG, Q0,Q1,Q2,Q3,Q4,Q5,Q6) \
  asm volatile( \
    "s_load_dwordx4 %0, %[b], %c[o0]\n\t" \
    "s_load_dwordx4 %1, %[b], %c[o1]\n\t" \
    "s_load_dwordx4 %2, %[b], %c[o2]\n\t" \
    "s_load_dwordx4 %3, %[b], %c[o3]\n\t" \
    "s_load_dwordx4 %4, %[b], %c[o4]\n\t" \
    "s_load_dwordx4 %5, %[b], %c[o5]\n\t" \
    "s_load_dwordx4 %6, %[b], %c[o6]\n\t" \
    "s_waitcnt lgkmcnt(0)" \
    : "=s"(Q0), "=s"(Q1), "=s"(Q2), "=s"(Q3), "=s"(Q4), "=s"(Q5), "=s"(Q6) \
    : [b]"s"(qbp), \
      [o0]"i"((CG)*16 + 0*256), [o1]"i"((CG)*16 + 1*256), \
      [o2]"i"((CG)*16 + 2*256), [o3]"i"((CG)*16 + 3*256), \
      [o4]"i"((CG)*16 + 4*256), [o5]"i"((CG)*16 + 5*256), \
      [o6]"i"((CG)*16 + 6*256))

#define CGSTEP(CG) { \
    f4s q0,q1,q2,q3,q4,q5,q6; \
    QLOAD(CG, q0,q1,q2,q3,q4,q5,q6); \
    float4 cl = *(const float4*)&cls[lane * 68 + (CG) * 4]; \
    acc[0]=fmaf(q0.x,cl.x,fmaf(q0.y,cl.y,fmaf(q0.z,cl.z,fmaf(q0.w,cl.w,acc[0])))); \
    acc[1]=fmaf(q1.x,cl.x,fmaf(q1.y,cl.y,fmaf(q1.z,cl.z,fmaf(q1.w,cl.w,acc[1])))); \
    acc[2]=fmaf(q2.x,cl.x,fmaf(q2.y,cl.y,fmaf(q2.z,cl.z,fmaf(q2.w,cl.w,acc[2])))); \
    acc[3]=fmaf(q3.x,cl.x,fmaf(q3.y,cl.y,fmaf(q3.z,cl.z,fmaf(q3.w,cl.w,acc[3])))); \
    acc[4]=fmaf(q4.x,cl.x,fmaf(q4.y,cl.y,fmaf(q4.z,cl.z,fmaf(q4.w,cl.w,acc[4])))); \
    acc[5]=fmaf(q5.x,cl.x,fmaf(q5.y,cl.y,fmaf(q5.z,cl.z,fmaf(q5.w,cl.w,acc[5])))); \
    acc[6]=fmaf(q6.x,cl.x,fmaf(q6.y,cl.y,fmaf(q6.z,cl.z,fmaf(q6.w,cl.w,acc[6])))); }

// ============================================================
// Round-16: ONE cooperative kernel for the whole pipeline.
// Diagnosis: non-kc1 time pinned at 136+-1us across r2/r5/r7 kernel
// rewrites; summed exec estimates ~25us => ~110us is dispatch
// overhead (7 dispatches x ~15us). Fix: fuse all 6 kernels + memset
// into one hipLaunchCooperativeKernel with grid.sync() between
// phases. Phase bodies are the r5/r7 bench-proven code, wrapped in
// grid-stride loops; LDS = 34816B union (kb's uls is max) -> 4
// blocks/CU via __launch_bounds__(256,4); grid sized by occupancy
// query, capped at 1024 (= kb's 4/CU co-residency).
// ============================================================
__global__ __launch_bounds__(256, 4) void fused(
    const float* __restrict__ sup, const float* __restrict__ qry,
    const float* __restrict__ unl, const int* __restrict__ qy,
    float* __restrict__ out, float* __restrict__ ws)
{
    __shared__ __align__(16) float smem[8704];
    cg::grid_group gridg = cg::this_grid();

    float* unl_n = ws + OF_UNL;
    float* sup_n = ws + OF_SUP;
    float* supT  = ws + OF_SUPT;
    float* qt    = ws + OF_QT;
    float* rowv  = ws + OF_ROWV;
    int*   rowi  = (int*)(ws + OF_ROWI);
    float* colvi = ws + OF_CVI;
    int*   cmp   = (int*)(ws + OF_CMP);
    int*   cntg  = (int*)(ws + OF_CNT);
    int*   unear = (int*)(ws + OF_UNEAR);
    int*   snear = (int*)(ws + OF_SNEAR);
    float* bvg   = ws + OF_BV;
    int*   bpg   = (int*)(ws + OF_BP);
    unsigned char* amaxg = (unsigned char*)(ws + OF_AMX);

    int tid = threadIdx.x;
    int lane = tid & 63, wv = tid >> 6;
    int bid = blockIdx.x, nblk = gridDim.x;

    // ================= P1: normalize (r7 body) =================
    if (bid == 0 && tid == 0) *out = 0.f;      // replaces hipMemsetAsync
    for (int u0 = bid; u0 < 200; u0 += nblk) {
        int unit = u0 * 4 + wv;                // 0..799
        float* lsw  = smem + wv * 1600;
        float* sclw = smem + 6400 + wv * 32;

        const float* src;
        float* dstT; float* dst2 = nullptr; int dst2_shot = 0; bool isq = false;
        if (unit < 400) {
            int b = unit / 100, u = unit % 100;
            src  = unl + (size_t)unit * 1600;
            dstT = unl_n + ((size_t)(b * 2500 + u * 25)) * 64;
        } else if (unit < 500) {
            int idx2 = unit - 400;
            int b = idx2 / 25, r = idx2 % 25;
            int w = r / 5, shot = r % 5;
            src  = sup + (size_t)(b * 25 + r) * 1600;
            dstT = sup_n + ((size_t)(b * 625 + w * 125 + shot * 25)) * 64;
            dst2 = supT + ((size_t)(b * 5 + w) * 64) * 128;
            dst2_shot = shot * 25;
        } else {
            int bq = unit - 500;
            src  = qry + (size_t)bq * 1600;
            dstT = qt + (size_t)bq * 1792;
            isq = true;
        }

        const float4* s4 = (const float4*)src;
#pragma unroll
        for (int k = 0; k < 7; ++k) {
            int idx = k * 64 + lane;
            if (idx < 400) *(float4*)&lsw[idx * 4] = s4[idx];
        }
        __syncthreads();
        if (lane < 25) {
            int hw = lane;
            float p[16];
#pragma unroll
            for (int sub = 0; sub < 16; ++sub) {
                float s = 0.f;
#pragma unroll
                for (int j = 0; j < 4; ++j) {
                    float v = lsw[(sub * 4 + j) * 25 + hw];
                    s += v * v;
                }
                p[sub] = s;
            }
#pragma unroll
            for (int st = 1; st < 16; st <<= 1)
#pragma unroll
                for (int i = 0; i < 16; i += 2 * st)
                    p[i] = p[i] + p[i + st];
            sclw[hw] = 1.f / fmaxf(sqrtf(p[0]), 1e-12f);
        }
        __syncthreads();
        float4* d4 = (float4*)dstT;
#pragma unroll
        for (int k = 0; k < 7; ++k) {
            int idx = k * 64 + lane;
            if (idx < 400) {
                int f = idx * 4;
                int r_ = f >> 6;
                int c0 = f & 63;
                float m = sclw[r_];
                float4 o;
                o.x = lsw[ c0      * 25 + r_] * m;
                o.y = lsw[(c0 + 1) * 25 + r_] * m;
                o.z = lsw[(c0 + 2) * 25 + r_] * m;
                o.w = lsw[(c0 + 3) * 25 + r_] * m;
                d4[idx] = o;
            }
        }
        if (isq && lane < 48) d4[400 + lane] = make_float4(0.f, 0.f, 0.f, 0.f);
        if (dst2) {
#pragma unroll
            for (int k = 0; k < 25; ++k) {
                int idx = k * 64 + lane;
                int c = idx / 25, hw2 = idx % 25;
                dst2[(size_t)c * 128 + dst2_shot + hw2] = lsw[idx] * sclw[hw2];
            }
        }
        __syncthreads();                       // LDS reuse across u0 iters
    }
    gridg.sync();

    // ================= P2: kb (r5 body) =================
    for (int vb = bid; vb < 1600; vb += nblk) {
        int nc = vb & 3;
        int mb = (vb >> 2) % 20;
        int bw = vb / 80;
        int b  = bw / 5;
        float* uls = smem;                          // 128*66 = 8448
        float* sv_f = smem + 8448;                  // 4*32
        int*   si_  = (int*)(smem + 8448 + 128);    // 4*32

        int m0 = mb * 128;
        int n0 = nc * 32;

        for (int i = tid; i < 128 * 16; i += 256) {
            int row = i >> 4, c4 = (i & 15) * 4;
            int m = m0 + row;
            float4 x = make_float4(0.f, 0.f, 0.f, 0.f);
            if (m < 2500) x = *(const float4*)(unl_n + ((size_t)(b * 2500 + m)) * 64 + c4);
            *(float2*)&uls[row * 66 + c4]     = make_float2(x.x, x.y);
            *(float2*)&uls[row * 66 + c4 + 2] = make_float2(x.z, x.w);
        }
        __syncthreads();

        int ml = tid & 127;
        int m  = m0 + ml;
        int nh = tid >> 7;
        int nbase = nh * 16;
        int nbu = __builtin_amdgcn_readfirstlane(nbase);
        int nn_total = (125 - n0) < 32 ? (125 - n0) : 32;
        const float* sbp = supT + ((size_t)bw * 64) * 128 + n0 + nbu;

        float acc[16];
#pragma unroll
        for (int j = 0; j < 16; ++j) acc[j] = 0.f;

        KB8(0)  KB8(8)  KB8(16) KB8(24)
        KB8(32) KB8(40) KB8(48) KB8(56)

        int nnloc = nn_total - nbase;
        nnloc = nnloc < 0 ? 0 : (nnloc > 16 ? 16 : nnloc);
        float rbv = NEGINF; int rbi = 0;
        for (int j = 0; j < nnloc; ++j)
            if (acc[j] > rbv) { rbv = acc[j]; rbi = n0 + nbase + j; }
        if (m < 2500) {
            int ck = nc * 2 + nh;
            rowv[((size_t)bw * 8 + ck) * 2500 + m] = rbv;
            rowi[((size_t)bw * 8 + ck) * 2500 + m] = rbi;
        }

#pragma unroll
        for (int j = 0; j < 16; ++j) {
            float v = (m < 2500 && (nbase + j) < nn_total) ? acc[j] : NEGINF;
            float vm = v;
#pragma unroll
            for (int s2 = 1; s2 < 64; s2 <<= 1) vm = fmaxf(vm, __shfl_xor(vm, s2));
            unsigned long long msk = __ballot(v == vm);
            int first = __ffsll((unsigned long long)msk) - 1;
            if (lane == 0) { sv_f[wv * 32 + nbase + j] = vm; si_[wv * 32 + nbase + j] = m0 + (wv & 1) * 64 + first; }
        }
        __syncthreads();
        if (tid < nn_total) {
            int w0 = (tid < 16) ? 0 : 2;
            float v = sv_f[w0 * 32 + tid];       int vi = si_[w0 * 32 + tid];
            float v2 = sv_f[(w0 + 1) * 32 + tid]; int i2 = si_[(w0 + 1) * 32 + tid];
            if (v2 > v || (v2 == v && i2 < vi)) { v = v2; vi = i2; }
            float* cv = colvi + ((((size_t)bw) * 125 + (n0 + tid)) * 20 + mb) * 2;
            cv[0] = v; ((int*)cv)[1] = vi;
        }
        __syncthreads();                       // LDS reuse across vb iters
    }
    gridg.sync();

    // ================= P3: kmerge (r5 body) =================
    for (int it = bid * 256 + tid; it < 12500; it += nblk * 256) {
        if (it < 10000) {
            int b = it / 2500, m = it % 2500;
            float bv = NEGINF; int bi = 0;
#pragma unroll
            for (int w = 0; w < 5; ++w) {
#pragma unroll
                for (int ck = 0; ck < 8; ++ck) {
                    size_t o = (((size_t)(b * 5 + w)) * 8 + ck) * 2500 + m;
                    float v = rowv[o];
                    if (v > bv) { bv = v; bi = w * 125 + rowi[o]; }
                }
            }
            unear[it] = bi;
        } else {
            int idx = it - 10000;
            const float* p = colvi + (size_t)idx * 40;
            float bv = NEGINF; int bi = 0x7fffffff;
            for (int mb2 = 0; mb2 < 20; ++mb2) {
                float v = p[mb2 * 2]; int vi = ((const int*)p)[mb2 * 2 + 1];
                if (v > bv || (v == bv && vi < bi)) { bv = v; bi = vi; }
            }
            snear[idx] = bi;
        }
    }
    gridg.sync();

    // ================= P4: kcmp (r5 body) =================
    for (int p = bid; p < 20; p += nblk) {
        int b = p / 5, way = p % 5;
        unsigned long long* masks = (unsigned long long*)smem;   // 40 ULL
        int* base = (int*)(smem + 80);                           // 40 int

        for (int ch = wv; ch < 40; ch += 4) {
            int m = ch * 64 + lane;
            bool ok = false;
            if (m < 2500) {
                int un = unear[b * 2500 + m];
                ok = (un / 125 == way) && (snear[b * 625 + un] == m);
            }
            unsigned long long msk = __ballot(ok ? 1 : 0);
            if (lane == 0) masks[ch] = msk;
        }
        __syncthreads();
        if (tid == 0) {
            int s = 0;
            for (int ch = 0; ch < 40; ++ch) { base[ch] = s; s += __popcll(masks[ch]); }
            cntg[p] = s;
        }
        __syncthreads();
        for (int ch = wv; ch < 40; ch += 4) {
            unsigned long long msk = masks[ch];
            if ((msk >> lane) & 1ull) {
                int pre = __popcll(msk & ((1ull << lane) - 1ull));
                cmp[(size_t)p * 2500 + base[ch] + pre] = ch * 64 + lane;
            }
        }
        __syncthreads();
    }
    gridg.sync();

    // ================= P5: kc1 (r5 body) =================
    for (int vb = bid; vb < 1500; vb += nblk) {
        int w = vb % 5, bq = vb / 5;
        int b = bq / 75;
        int wvu = __builtin_amdgcn_readfirstlane(tid >> 6);
        int pbw = b * 5 + w;

        int L = 0;
#pragma unroll
        for (int i = 0; i < 20; ++i) { int v = cntg[i]; L = L > v ? L : v; }
        int cntw = 0, wb = 0;
#pragma unroll
        for (int w2 = 0; w2 < 5; ++w2) {
            int c2 = cntg[b * 5 + w2];
            if (w2 < w) wb += 125 + c2;
            if (w2 == w) cntw = c2;
        }
        int cw = 125 + cntw;

        float* cls   = smem;                       // 64*68 = 4352
        float* amxv  = smem + 4352;                // 4*64
        int*   amxg_ = (int*)(smem + 4608);        // 4*64
        float* redv  = smem + 4864;                // 25
        int*   redn  = (int*)(smem + 4889);        // 25

        const float* qbp = qt + ((size_t)bq * 28 + wvu * 7) * 64;

        float rv[7]; int rn[7];
#pragma unroll
        for (int j = 0; j < 7; ++j) { rv[j] = NEGINF; rn[j] = 0x7fffffff; }

        int nb = (cw + 63) >> 6;

        for (int b4 = 0; b4 < nb; ++b4) {
            if (b4 > 0 && tid < 64) {
                int n = (b4 - 1) * 64 + tid;
                if (n < cw) {
                    float v = amxv[tid]; int g = amxg_[tid];
#pragma unroll
                    for (int g2 = 1; g2 < 4; ++g2)
                        if (amxv[g2 * 64 + tid] > v) { v = amxv[g2 * 64 + tid]; g = amxg_[g2 * 64 + tid]; }
                    amaxg[(size_t)bq * 3200 + (wb + n)] = (unsigned char)g;
                }
            }
#pragma unroll
            for (int k = 0; k < 4; ++k) {
                int i = tid + k * 256;
                int row = i >> 4, ch = i & 15;
                int n = b4 * 64 + row;
                float4 x = make_float4(0.f, 0.f, 0.f, 0.f);
                if (n < cw) {
                    const float* cp;
                    if (n < 125) cp = sup_n + (((size_t)pbw) * 125 + n) * 64;
                    else { int m = cmp[((size_t)pbw) * 2500 + (n - 125)];
                           cp = unl_n + ((size_t)(b * 2500 + m)) * 64; }
                    x = *(const float4*)(cp + ch * 4);
                }
                *(float4*)&cls[row * 68 + ch * 4] = x;
            }
            __syncthreads();

            float acc[7];
#pragma unroll
            for (int j = 0; j < 7; ++j) acc[j] = 0.f;

            CGSTEP(0);  CGSTEP(1);  CGSTEP(2);  CGSTEP(3);
            CGSTEP(4);  CGSTEP(5);  CGSTEP(6);  CGSTEP(7);
            CGSTEP(8);  CGSTEP(9);  CGSTEP(10); CGSTEP(11);
            CGSTEP(12); CGSTEP(13); CGSTEP(14); CGSTEP(15);

            bool colvalid = (b4 * 64 + lane) < cw;
            float cmax = NEGINF; int cam = 0;
#pragma unroll
            for (int j = 0; j < 7; ++j) {
                int mq = wvu * 7 + j;
                float s = (acc[j] + 1.0f) * 0.5f;
                float sm = (colvalid && mq < 25) ? s : NEGINF;
                if (sm > cmax) { cmax = sm; cam = mq; }
                float vm = sm;
#pragma unroll
                for (int t = 1; t < 64; t <<= 1) vm = fmaxf(vm, __shfl_xor(vm, t));
                unsigned long long msk = __ballot(sm == vm);
                int first = __ffsll(msk) - 1;
                if (vm > rv[j]) { rv[j] = vm; rn[j] = b4 * 64 + first; }
            }
            amxv[wvu * 64 + lane] = cmax; amxg_[wvu * 64 + lane] = cam;
            __syncthreads();
        }

        if (tid < 64) {
            int n = (nb - 1) * 64 + tid;
            if (n < cw) {
                float v = amxv[tid]; int g = amxg_[tid];
#pragma unroll
                for (int g2 = 1; g2 < 4; ++g2)
                    if (amxv[g2 * 64 + tid] > v) { v = amxv[g2 * 64 + tid]; g = amxg_[g2 * 64 + tid]; }
                amaxg[(size_t)bq * 3200 + (wb + n)] = (unsigned char)g;
            }
        }
        if (lane == 0) {
#pragma unroll
            for (int j = 0; j < 7; ++j) {
                int mq = wvu * 7 + j;
                if (mq < 25) { redv[mq] = rv[j]; redn[mq] = rn[j]; }
            }
        }
        __syncthreads();

        if (tid < 25) {
            float v = redv[tid]; int nn = redn[tid];
            int p = ((w * 2625 + nn) << 12) | (wb + nn);
            if (L > cntw) {
                int pp = ((w * 2625 + 125 + cntw) << 12) | 0xFFF;
                if (0.5f > v || (0.5f == v && pp < p)) { v = 0.5f; p = pp; }
            }
            size_t o = ((size_t)bq * 5 + w) * 25 + tid;
            bvg[o] = v; bpg[o] = p;
        }
        __syncthreads();                       // LDS reuse across vb iters
    }
    gridg.sync();

    // ================= P6: kce (r5 body, per-block) =================
    for (int bq = bid; bq < 300; bq += nblk) {
        float* qmask = smem;                   // 25
        float* lg    = smem + 25;              // 5
        if (tid < 25) {
            float v = NEGINF; int p = 0x7fffffff;
#pragma unroll
            for (int w = 0; w < 5; ++w) {
                size_t o = ((size_t)bq * 5 + w) * 25 + tid;
                float v2 = bvg[o]; int p2 = bpg[o];
                if (v2 > v || (v2 == v && p2 < p)) { v = v2; p = p2; }
            }
            int pos = p & 0xFFF;
            int g = (pos == 0xFFF) ? 0 : (int)amaxg[(size_t)bq * 3200 + pos];
            qmask[tid] = (g == tid) ? 1.0f : 0.0f;
        }
        __syncthreads();
        if (tid < 5) {
            float s = 0.f;
#pragma unroll
            for (int mq = 0; mq < 25; ++mq)
                s += bvg[((size_t)bq * 5 + tid) * 25 + mq] * qmask[mq];
            lg[tid] = s;
        }
        __syncthreads();
        if (tid == 0) {
            int y = qy[bq];
            float mx = lg[0];
#pragma unroll
            for (int w = 1; w < 5; ++w) mx = fmaxf(mx, lg[w]);
            float se = 0.f;
#pragma unroll
            for (int w = 0; w < 5; ++w) se += expf(lg[w] - mx);
            float loss = -(lg[y] - mx - logf(se));
            atomicAdd(out, loss * (1.0f / 300.0f));
        }
        __syncthreads();
    }
}

// ============================================================
extern "C" void kernel_launch(void* const* d_in, const int* in_sizes, int n_in,
                              void* d_out, int out_size, void* d_ws, size_t ws_size,
                              hipStream_t stream)
{
    const float* sup = (const float*)d_in[0];
    const float* qry = (const float*)d_in[2];
    const int*   qy  = (const int*)d_in[3];
    const float* unl = (const float*)d_in[4];
    float* outp = (float*)d_out;
    float* ws   = (float*)d_ws;

    static int maxb = 0;
    if (maxb == 0) {
        hipOccupancyMaxActiveBlocksPerMultiprocessor(&maxb, fused, 256, 0);
        if (maxb < 1) maxb = 1;
    }
    int grid = maxb * 256;
    if (grid > 1024) grid = 1024;

    void* args[] = { (void*)&sup, (void*)&qry, (void*)&unl,
                     (void*)&qy, (void*)&outp, (void*)&ws };
    hipLaunchCooperativeKernel(fused, dim3(grid), dim3(256), args, 0, stream);
}

// Round 10
// 286.800 us; speedup vs baseline: 1.7682x; 1.7682x over previous
//
#include <hip/hip_runtime.h>

#define NEGINF (-1e30f)

// ---------------- problem constants ----------------
// b=4, c=64, h=w=5, q=75, u=100, N_WAY=5, K_SHOT=5
// M_s = 125 (per way), M_u = 2500, M_q = 25, M_tot = 2625
// ---------------- workspace layout (float units) ----------------
// Round-5 proven layout. kmerge is GONE (r9): rowv/rowi/colvi are
// dead; their space hosts the atomic argmax keys + the kc1 block
// counter. unear/snear int arrays also dead (kcmp decodes keys).
constexpr size_t OF_UNL  = 0;                              // [4][2500][64]
constexpr size_t OF_SUP  = OF_UNL  + (size_t)4*2500*64;    // [4][5][125][64]
constexpr size_t OF_SUPT = OF_SUP  + (size_t)4*5*125*64;   // [4][5][64][128]
constexpr size_t OF_QT   = OF_SUPT + (size_t)4*5*64*128;   // [300][28][64]
constexpr size_t OF_ROWV = OF_QT   + (size_t)300*28*64;    // (dead rowv space)
constexpr size_t OF_UKEY = OF_ROWV;                        // [4][2500] u64 keys
constexpr size_t OF_SKEY = OF_ROWV + 20000;                // [4][625]  u64 keys
constexpr size_t OF_CBQ  = OF_ROWV + 25000;                // [300] int
constexpr size_t OF_CVI  = OF_ROWV + (size_t)2*4*5*8*2500; // (dead)
constexpr size_t OF_CMP  = OF_CVI  + (size_t)4*5*125*20*2; // [4][5][2500] i
constexpr size_t OF_CNT  = OF_CMP  + (size_t)4*5*2500;     // [20] i
constexpr size_t OF_UNEAR= OF_CNT  + 20;                   // (dead)
constexpr size_t OF_SNEAR= OF_UNEAR+ 10000;                // (dead)
constexpr size_t OF_BV   = OF_SNEAR+ 2500;                 // [300][5][25] f
constexpr size_t OF_BP   = OF_BV   + 37500;                // [300][5][25] i
constexpr size_t OF_AMX  = OF_BP   + 37500;                // [300][3200] u8

typedef __attribute__((ext_vector_type(4)))  float f4s;
typedef __attribute__((ext_vector_type(16))) float f16s;

__device__ __forceinline__ unsigned long long pack_key(float v, int idx) {
    unsigned int e = __float_as_uint(v);
    e ^= (e >> 31) ? 0xFFFFFFFFu : 0x80000000u;   // order-isomorphic f32->u32
    return ((unsigned long long)e << 32) | (unsigned int)~idx;  // tie -> min idx
}

// ============================================================
// Kernel A: L2-normalize (r7/r8 bench-proven body) + zero out,
// argmax keys, and the kc1 block counter (replaces memset+kmerge init).
// ============================================================
__global__ __launch_bounds__(256) void knorm(
    const float* __restrict__ sup, const float* __restrict__ qry,
    const float* __restrict__ unl, float* __restrict__ ws,
    float* __restrict__ out)
{
    float* unl_n = ws + OF_UNL;
    float* sup_n = ws + OF_SUP;
    float* supT  = ws + OF_SUPT;
    float* qt    = ws + OF_QT;

    int tid = threadIdx.x;
    int lane = tid & 63, wv = tid >> 6;
    int gid = blockIdx.x * 256 + tid;

    if (gid == 0) *out = 0.f;
    if (gid < 25300) ((unsigned int*)(ws + OF_UKEY))[gid] = 0u;  // keys + cnt_bq

    int unit = blockIdx.x * 4 + wv;      // 0..799

    __shared__ float ls[4][1600];
    __shared__ float scl[4][32];

    const float* src;
    float* dstT; float* dst2 = nullptr; int dst2_shot = 0; bool isq = false;

    if (unit < 400) {
        int b = unit / 100, u = unit % 100;
        src  = unl + (size_t)unit * 1600;
        dstT = unl_n + ((size_t)(b * 2500 + u * 25)) * 64;
    } else if (unit < 500) {
        int idx2 = unit - 400;
        int b = idx2 / 25, r = idx2 % 25;
        int w = r / 5, shot = r % 5;
        src  = sup + (size_t)(b * 25 + r) * 1600;
        dstT = sup_n + ((size_t)(b * 625 + w * 125 + shot * 25)) * 64;
        dst2 = supT + ((size_t)(b * 5 + w) * 64) * 128;
        dst2_shot = shot * 25;
    } else {
        int bq = unit - 500;
        src  = qry + (size_t)bq * 1600;
        dstT = qt + (size_t)bq * 1792;
        isq = true;
    }

    const float4* s4 = (const float4*)src;
#pragma unroll
    for (int k = 0; k < 7; ++k) {
        int idx = k * 64 + lane;
        if (idx < 400) *(float4*)&ls[wv][idx * 4] = s4[idx];
    }
    __syncthreads();

    if (lane < 25) {
        int hw = lane;
        float p[16];
#pragma unroll
        for (int sub = 0; sub < 16; ++sub) {
            float s = 0.f;
#pragma unroll
            for (int j = 0; j < 4; ++j) {
                float v = ls[wv][(sub * 4 + j) * 25 + hw];
                s += v * v;
            }
            p[sub] = s;
        }
#pragma unroll
        for (int st = 1; st < 16; st <<= 1)
#pragma unroll
            for (int i = 0; i < 16; i += 2 * st)
                p[i] = p[i] + p[i + st];
        scl[wv][hw] = 1.f / fmaxf(sqrtf(p[0]), 1e-12f);
    }
    __syncthreads();

    float4* d4 = (float4*)dstT;
#pragma unroll
    for (int k = 0; k < 7; ++k) {
        int idx = k * 64 + lane;
        if (idx < 400) {
            int f = idx * 4;
            int r_ = f >> 6;
            int c0 = f & 63;
            float m = scl[wv][r_];
            float4 o;
            o.x = ls[wv][ c0      * 25 + r_] * m;
            o.y = ls[wv][(c0 + 1) * 25 + r_] * m;
            o.z = ls[wv][(c0 + 2) * 25 + r_] * m;
            o.w = ls[wv][(c0 + 3) * 25 + r_] * m;
            d4[idx] = o;
        }
    }
    if (isq && lane < 48) d4[400 + lane] = make_float4(0.f, 0.f, 0.f, 0.f);
    if (dst2) {
#pragma unroll
        for (int k = 0; k < 25; ++k) {
            int idx = k * 64 + lane;
            int c = idx / 25, hw2 = idx % 25;
            dst2[(size_t)c * 128 + dst2_shot + hw2] = ls[wv][idx] * scl[wv][hw2];
        }
    }
}

// ============================================================
// Kernel B: u2s pass (r5 bench-proven compute). Round-17 change:
// row/col argmax partials published via atomicMax on packed u64
// keys (order-encoded value<<32 | ~idx) -> kmerge ELIMINATED.
// Max-key == (max v, tie -> min idx), identical to kmerge's scan.
// ============================================================
#define KB2(C) { \
    f16s s0, s1; \
    asm volatile("s_load_dwordx16 %0, %[b], %c[o0]\n\t" \
                 "s_load_dwordx16 %1, %[b], %c[o1]\n\t" \
                 "s_waitcnt lgkmcnt(0)" \
                 : "=s"(s0), "=s"(s1) \
                 : [b]"s"(sbp), [o0]"i"((C)*512), [o1]"i"((C)*512+512)); \
    float2 uv = *(const float2*)&uls[ml * 66 + (C)]; \
    acc[0]  = fmaf(uv.x, s0[0],  fmaf(uv.y, s1[0],  acc[0])); \
    acc[1]  = fmaf(uv.x, s0[1],  fmaf(uv.y, s1[1],  acc[1])); \
    acc[2]  = fmaf(uv.x, s0[2],  fmaf(uv.y, s1[2],  acc[2])); \
    acc[3]  = fmaf(uv.x, s0[3],  fmaf(uv.y, s1[3],  acc[3])); \
    acc[4]  = fmaf(uv.x, s0[4],  fmaf(uv.y, s1[4],  acc[4])); \
    acc[5]  = fmaf(uv.x, s0[5],  fmaf(uv.y, s1[5],  acc[5])); \
    acc[6]  = fmaf(uv.x, s0[6],  fmaf(uv.y, s1[6],  acc[6])); \
    acc[7]  = fmaf(uv.x, s0[7],  fmaf(uv.y, s1[7],  acc[7])); \
    acc[8]  = fmaf(uv.x, s0[8],  fmaf(uv.y, s1[8],  acc[8])); \
    acc[9]  = fmaf(uv.x, s0[9],  fmaf(uv.y, s1[9],  acc[9])); \
    acc[10] = fmaf(uv.x, s0[10], fmaf(uv.y, s1[10], acc[10])); \
    acc[11] = fmaf(uv.x, s0[11], fmaf(uv.y, s1[11], acc[11])); \
    acc[12] = fmaf(uv.x, s0[12], fmaf(uv.y, s1[12], acc[12])); \
    acc[13] = fmaf(uv.x, s0[13], fmaf(uv.y, s1[13], acc[13])); \
    acc[14] = fmaf(uv.x, s0[14], fmaf(uv.y, s1[14], acc[14])); \
    acc[15] = fmaf(uv.x, s0[15], fmaf(uv.y, s1[15], acc[15])); }
#define KB8(C) KB2(C) KB2((C)+2) KB2((C)+4) KB2((C)+6)

__global__ __launch_bounds__(256) void kb(
    const float* __restrict__ unl_n, const float* __restrict__ supT,
    unsigned long long* __restrict__ ukey, unsigned long long* __restrict__ skey)
{
    int bid = blockIdx.x;
    int nc = bid & 3;
    int mb = (bid >> 2) % 20;
    int bw = bid / 80;               // b*5+w
    int b  = bw / 5;
    int w  = bw % 5;
    int tid = threadIdx.x;
    int lane = tid & 63, wv = tid >> 6;

    __shared__ float uls[128 * 66];
    __shared__ float sv_[4][32];
    __shared__ int   si_[4][32];

    int m0 = mb * 128;
    int n0 = nc * 32;

    for (int i = tid; i < 128 * 16; i += 256) {
        int row = i >> 4, c4 = (i & 15) * 4;
        int m = m0 + row;
        float4 x = make_float4(0.f, 0.f, 0.f, 0.f);
        if (m < 2500) x = *(const float4*)(unl_n + ((size_t)(b * 2500 + m)) * 64 + c4);
        *(float2*)&uls[row * 66 + c4]     = make_float2(x.x, x.y);
        *(float2*)&uls[row * 66 + c4 + 2] = make_float2(x.z, x.w);
    }
    __syncthreads();

    int ml = tid & 127;
    int m  = m0 + ml;
    int nh = tid >> 7;
    int nbase = nh * 16;
    int nbu = __builtin_amdgcn_readfirstlane(nbase);
    int nn_total = (125 - n0) < 32 ? (125 - n0) : 32;
    const float* sbp = supT + ((size_t)bw * 64) * 128 + n0 + nbu;

    float acc[16];
#pragma unroll
    for (int j = 0; j < 16; ++j) acc[j] = 0.f;

    KB8(0)  KB8(8)  KB8(16) KB8(24)
    KB8(32) KB8(40) KB8(48) KB8(56)

    // row-side running argmax -> atomic key (was rowv/rowi + kmerge)
    int nnloc = nn_total - nbase;
    nnloc = nnloc < 0 ? 0 : (nnloc > 16 ? 16 : nnloc);
    float rbv = NEGINF; int rbi = 0;
    for (int j = 0; j < nnloc; ++j)
        if (acc[j] > rbv) { rbv = acc[j]; rbi = n0 + nbase + j; }
    if (m < 2500)
        atomicMax(ukey + (b * 2500 + m), pack_key(rbv, w * 125 + rbi));

    // col-side: wave max + ballot/ffs min-m tie-break -> atomic key
#pragma unroll
    for (int j = 0; j < 16; ++j) {
        float v = (m < 2500 && (nbase + j) < nn_total) ? acc[j] : NEGINF;
        float vm = v;
#pragma unroll
        for (int s2 = 1; s2 < 64; s2 <<= 1) vm = fmaxf(vm, __shfl_xor(vm, s2));
        unsigned long long msk = __ballot(v == vm);
        int first = __ffsll((unsigned long long)msk) - 1;
        if (lane == 0) { sv_[wv][nbase + j] = vm; si_[wv][nbase + j] = m0 + (wv & 1) * 64 + first; }
    }
    __syncthreads();
    if (tid < nn_total) {
        int w0 = (tid < 16) ? 0 : 2;
        float v = sv_[w0][tid];     int vi = si_[w0][tid];
        float v2 = sv_[w0 + 1][tid]; int i2 = si_[w0 + 1][tid];
        if (v2 > v || (v2 == v && i2 < vi)) { v = v2; vi = i2; }
        atomicMax(skey + (bw * 125 + n0 + tid), pack_key(v, vi));
    }
}

// ============================================================
// Kernel P: mutual-NN mask + stable compaction. 20 blocks x 256.
// (r5 body; decodes the atomic keys in place of unear/snear)
// ============================================================
__global__ __launch_bounds__(256) void kcmp(
    const unsigned long long* __restrict__ ukey,
    const unsigned long long* __restrict__ skey,
    int* __restrict__ cmp, int* __restrict__ cntg)
{
    int p = blockIdx.x;
    int b = p / 5, way = p % 5;
    int tid = threadIdx.x, lane = tid & 63, wv = tid >> 6;
    __shared__ unsigned long long masks[40];
    __shared__ int base[40];

    for (int ch = wv; ch < 40; ch += 4) {
        int m = ch * 64 + lane;
        bool ok = false;
        if (m < 2500) {
            int un = (int)(~(unsigned int)ukey[b * 2500 + m]);   // w*125+n
            ok = (un / 125 == way) &&
                 ((int)(~(unsigned int)skey[b * 625 + un]) == m);
        }
        unsigned long long msk = __ballot(ok ? 1 : 0);
        if (lane == 0) masks[ch] = msk;
    }
    __syncthreads();
    if (tid == 0) {
        int s = 0;
        for (int ch = 0; ch < 40; ++ch) { base[ch] = s; s += __popcll(masks[ch]); }
        cntg[p] = s;
    }
    __syncthreads();
    for (int ch = wv; ch < 40; ch += 4) {
        unsigned long long msk = masks[ch];
        if ((msk >> lane) & 1ull) {
            int pre = __popcll(msk & ((1ull << lane) - 1ull));
            cmp[(size_t)p * 2500 + base[ch] + pre] = ch * 64 + lane;
        }
    }
}

// ============================================================
// Kernel C1 (r5 bench-proven body) + fused kce: the LAST of the 5
// (bq,w) blocks (device-scope counter) merges bvg/bpg/amaxg via
// agent-scope acquire loads and computes the row loss.
// ============================================================
#define QLOAD(CG, Q0,Q1,Q2,Q3,Q4,Q5,Q6) \
  asm volatile( \
    "s_load_dwordx4 %0, %[b], %c[o0]\n\t" \
    "s_load_dwordx4 %1, %[b], %c[o1]\n\t" \
    "s_load_dwordx4 %2, %[b], %c[o2]\n\t" \
    "s_load_dwordx4 %3, %[b], %c[o3]\n\t" \
    "s_load_dwordx4 %4, %[b], %c[o4]\n\t" \
    "s_load_dwordx4 %5, %[b], %c[o5]\n\t" \
    "s_load_dwordx4 %6, %[b], %c[o6]\n\t" \
    "s_waitcnt lgkmcnt(0)" \
    : "=s"(Q0), "=s"(Q1), "=s"(Q2), "=s"(Q3), "=s"(Q4), "=s"(Q5), "=s"(Q6) \
    : [b]"s"(qbp), \
      [o0]"i"((CG)*16 + 0*256), [o1]"i"((CG)*16 + 1*256), \
      [o2]"i"((CG)*16 + 2*256), [o3]"i"((CG)*16 + 3*256), \
      [o4]"i"((CG)*16 + 4*256), [o5]"i"((CG)*16 + 5*256), \
      [o6]"i"((CG)*16 + 6*256))

#define CGSTEP(CG) { \
    f4s q0,q1,q2,q3,q4,q5,q6; \
    QLOAD(CG, q0,q1,q2,q3,q4,q5,q6); \
    float4 cl = *(const float4*)&cls[lane * 68 + (CG) * 4]; \
    acc[0]=fmaf(q0.x,cl.x,fmaf(q0.y,cl.y,fmaf(q0.z,cl.z,fmaf(q0.w,cl.w,acc[0])))); \
    acc[1]=fmaf(q1.x,cl.x,fmaf(q1.y,cl.y,fmaf(q1.z,cl.z,fmaf(q1.w,cl.w,acc[1])))); \
    acc[2]=fmaf(q2.x,cl.x,fmaf(q2.y,cl.y,fmaf(q2.z,cl.z,fmaf(q2.w,cl.w,acc[2])))); \
    acc[3]=fmaf(q3.x,cl.x,fmaf(q3.y,cl.y,fmaf(q3.z,cl.z,fmaf(q3.w,cl.w,acc[3])))); \
    acc[4]=fmaf(q4.x,cl.x,fmaf(q4.y,cl.y,fmaf(q4.z,cl.z,fmaf(q4.w,cl.w,acc[4])))); \
    acc[5]=fmaf(q5.x,cl.x,fmaf(q5.y,cl.y,fmaf(q5.z,cl.z,fmaf(q5.w,cl.w,acc[5])))); \
    acc[6]=fmaf(q6.x,cl.x,fmaf(q6.y,cl.y,fmaf(q6.z,cl.z,fmaf(q6.w,cl.w,acc[6])))); }

__global__ __launch_bounds__(256) void kc1(
    const float* __restrict__ qt, const float* __restrict__ sup_n,
    const float* __restrict__ unl_n, const int* __restrict__ cmp,
    const int* __restrict__ cntg,
    float* __restrict__ bvg, int* __restrict__ bpg,
    unsigned char* __restrict__ amaxg, int* __restrict__ cntbq,
    const int* __restrict__ qy, float* __restrict__ out)
{
    int bid = blockIdx.x;
    int w = bid % 5, bq = bid / 5;
    int b = bq / 75;
    int tid = threadIdx.x;
    int lane = tid & 63;
    int wvu = __builtin_amdgcn_readfirstlane(tid >> 6);
    int pbw = b * 5 + w;

    int L = 0;
#pragma unroll
    for (int i = 0; i < 20; ++i) { int v = cntg[i]; L = L > v ? L : v; }
    int cntw = 0, wb = 0;
#pragma unroll
    for (int w2 = 0; w2 < 5; ++w2) {
        int c2 = cntg[b * 5 + w2];
        if (w2 < w) wb += 125 + c2;
        if (w2 == w) cntw = c2;
    }
    int cw = 125 + cntw;

    __shared__ float cls[64 * 68];
    __shared__ float amxv[4][64];
    __shared__ int   amxg_[4][64];
    __shared__ float redv[25];
    __shared__ int   redn[25];
    __shared__ int   lastf;
    __shared__ float qmask[25];
    __shared__ float lg[5];

    const float* qbp = qt + ((size_t)bq * 28 + wvu * 7) * 64;

    float rv[7]; int rn[7];
#pragma unroll
    for (int j = 0; j < 7; ++j) { rv[j] = NEGINF; rn[j] = 0x7fffffff; }

    int nb = (cw + 63) >> 6;

    for (int b4 = 0; b4 < nb; ++b4) {
        if (b4 > 0 && tid < 64) {
            int n = (b4 - 1) * 64 + tid;
            if (n < cw) {
                float v = amxv[0][tid]; int g = amxg_[0][tid];
#pragma unroll
                for (int g2 = 1; g2 < 4; ++g2)
                    if (amxv[g2][tid] > v) { v = amxv[g2][tid]; g = amxg_[g2][tid]; }
                amaxg[(size_t)bq * 3200 + (wb + n)] = (unsigned char)g;
            }
        }
#pragma unroll
        for (int k = 0; k < 4; ++k) {
            int i = tid + k * 256;
            int row = i >> 4, ch = i & 15;
            int n = b4 * 64 + row;
            float4 x = make_float4(0.f, 0.f, 0.f, 0.f);
            if (n < cw) {
                const float* cp;
                if (n < 125) cp = sup_n + (((size_t)pbw) * 125 + n) * 64;
                else { int m = cmp[((size_t)pbw) * 2500 + (n - 125)];
                       cp = unl_n + ((size_t)(b * 2500 + m)) * 64; }
                x = *(const float4*)(cp + ch * 4);
            }
            *(float4*)&cls[row * 68 + ch * 4] = x;
        }
        __syncthreads();

        float acc[7];
#pragma unroll
        for (int j = 0; j < 7; ++j) acc[j] = 0.f;

        CGSTEP(0);  CGSTEP(1);  CGSTEP(2);  CGSTEP(3);
        CGSTEP(4);  CGSTEP(5);  CGSTEP(6);  CGSTEP(7);
        CGSTEP(8);  CGSTEP(9);  CGSTEP(10); CGSTEP(11);
        CGSTEP(12); CGSTEP(13); CGSTEP(14); CGSTEP(15);

        bool colvalid = (b4 * 64 + lane) < cw;
        float cmax = NEGINF; int cam = 0;
#pragma unroll
        for (int j = 0; j < 7; ++j) {
            int mq = wvu * 7 + j;
            float s = (acc[j] + 1.0f) * 0.5f;
            float sm = (colvalid && mq < 25) ? s : NEGINF;
            if (sm > cmax) { cmax = sm; cam = mq; }
            float vm = sm;
#pragma unroll
            for (int t = 1; t < 64; t <<= 1) vm = fmaxf(vm, __shfl_xor(vm, t));
            unsigned long long msk = __ballot(sm == vm);
            int first = __ffsll(msk) - 1;
            if (vm > rv[j]) { rv[j] = vm; rn[j] = b4 * 64 + first; }
        }
        amxv[wvu][lane] = cmax; amxg_[wvu][lane] = cam;
        __syncthreads();
    }

    if (tid < 64) {
        int n = (nb - 1) * 64 + tid;
        if (n < cw) {
            float v = amxv[0][tid]; int g = amxg_[0][tid];
#pragma unroll
            for (int g2 = 1; g2 < 4; ++g2)
                if (amxv[g2][tid] > v) { v = amxv[g2][tid]; g = amxg_[g2][tid]; }
            amaxg[(size_t)bq * 3200 + (wb + n)] = (unsigned char)g;
        }
    }
    if (lane == 0) {
#pragma unroll
        for (int j = 0; j < 7; ++j) {
            int mq = wvu * 7 + j;
            if (mq < 25) { redv[mq] = rv[j]; redn[mq] = rn[j]; }
        }
    }
    __syncthreads();

    if (tid < 25) {
        float v = redv[tid]; int nn = redn[tid];
        int p = ((w * 2625 + nn) << 12) | (wb + nn);
        if (L > cntw) {
            int pp = ((w * 2625 + 125 + cntw) << 12) | 0xFFF;
            if (0.5f > v || (0.5f == v && pp < p)) { v = 0.5f; p = pp; }
        }
        size_t o = ((size_t)bq * 5 + w) * 25 + tid;
        bvg[o] = v; bpg[o] = p;
    }

    // ---- fused kce: last block of this bq computes the row loss ----
    __syncthreads();
    __threadfence();                               // release our bvg/bpg/amaxg
    if (tid == 0)
        lastf = (__hip_atomic_fetch_add(cntbq + bq, 1, __ATOMIC_ACQ_REL,
                                        __HIP_MEMORY_SCOPE_AGENT) == 4) ? 1 : 0;
    __syncthreads();
    if (!lastf) return;
    __threadfence();                               // acquire others' writes

    if (tid < 25) {
        float v = NEGINF; int p = 0x7fffffff;
#pragma unroll
        for (int w2 = 0; w2 < 5; ++w2) {
            size_t o = ((size_t)bq * 5 + w2) * 25 + tid;
            float v2 = __hip_atomic_load(&bvg[o], __ATOMIC_RELAXED, __HIP_MEMORY_SCOPE_AGENT);
            int   p2 = __hip_atomic_load(&bpg[o], __ATOMIC_RELAXED, __HIP_MEMORY_SCOPE_AGENT);
            if (v2 > v || (v2 == v && p2 < p)) { v = v2; p = p2; }
        }
        int pos = p & 0xFFF;
        int g = 0;
        if (pos != 0xFFF)
            g = (int)__hip_atomic_load(&amaxg[(size_t)bq * 3200 + pos],
                                       __ATOMIC_RELAXED, __HIP_MEMORY_SCOPE_AGENT);
        qmask[tid] = (g == tid) ? 1.0f : 0.0f;
    }
    __syncthreads();
    if (tid < 5) {
        float s = 0.f;
#pragma unroll
        for (int mq = 0; mq < 25; ++mq) {
            size_t o = ((size_t)bq * 5 + tid) * 25 + mq;
            float v2 = __hip_atomic_load(&bvg[o], __ATOMIC_RELAXED, __HIP_MEMORY_SCOPE_AGENT);
            s += v2 * qmask[mq];
        }
        lg[tid] = s;
    }
    __syncthreads();
    if (tid == 0) {
        int y = qy[bq];
        float mx = lg[0];
#pragma unroll
        for (int w2 = 1; w2 < 5; ++w2) mx = fmaxf(mx, lg[w2]);
        float se = 0.f;
#pragma unroll
        for (int w2 = 0; w2 < 5; ++w2) se += expf(lg[w2] - mx);
        float loss = -(lg[y] - mx - logf(se));
        atomicAdd(out, loss * (1.0f / 300.0f));
    }
}

// ============================================================
extern "C" void kernel_launch(void* const* d_in, const int* in_sizes, int n_in,
                              void* d_out, int out_size, void* d_ws, size_t ws_size,
                              hipStream_t stream)
{
    const float* sup = (const float*)d_in[0];
    const float* qry = (const float*)d_in[2];
    const int*   qy  = (const int*)d_in[3];
    const float* unl = (const float*)d_in[4];

    float* ws    = (float*)d_ws;
    float* unl_n = ws + OF_UNL;
    float* sup_n = ws + OF_SUP;
    float* supT  = ws + OF_SUPT;
    float* qt    = ws + OF_QT;
    unsigned long long* ukey = (unsigned long long*)(ws + OF_UKEY);
    unsigned long long* skey = (unsigned long long*)(ws + OF_SKEY);
    int*   cntbq = (int*)(ws + OF_CBQ);
    int*   cmp   = (int*)(ws + OF_CMP);
    int*   cntg  = (int*)(ws + OF_CNT);
    float* bvg   = ws + OF_BV;
    int*   bpg   = (int*)(ws + OF_BP);
    unsigned char* amaxg = (unsigned char*)(ws + OF_AMX);

    hipLaunchKernelGGL(knorm, dim3(200), dim3(256), 0, stream,
                       sup, qry, unl, ws, (float*)d_out);
    hipLaunchKernelGGL(kb, dim3(1600), dim3(256), 0, stream,
                       unl_n, supT, ukey, skey);
    hipLaunchKernelGGL(kcmp, dim3(20), dim3(256), 0, stream,
                       ukey, skey, cmp, cntg);
    hipLaunchKernelGGL(kc1, dim3(1500), dim3(256), 0, stream,
                       qt, sup_n, unl_n, cmp, cntg, bvg, bpg, amaxg,
                       cntbq, qy, (float*)d_out);
}

// Round 11
// 157.020 us; speedup vs baseline: 3.2297x; 1.8265x over previous
//
#include <hip/hip_runtime.h>

#define NEGINF (-1e30f)

// ---------------- problem constants ----------------
// b=4, c=64, h=w=5, q=75, u=100, N_WAY=5, K_SHOT=5
// M_s = 125 (per way), M_u = 2500, M_q = 25, M_tot = 2625
// ---------------- workspace layout (float units) ----------------
// r9 layout (HW-passed): kmerge dead; rowv/rowi space hosts atomic
// argmax keys (+ a counter slot, now unused but still zeroed).
constexpr size_t OF_UNL  = 0;                              // [4][2500][64]
constexpr size_t OF_SUP  = OF_UNL  + (size_t)4*2500*64;    // [4][5][125][64]
constexpr size_t OF_SUPT = OF_SUP  + (size_t)4*5*125*64;   // [4][5][64][128]
constexpr size_t OF_QT   = OF_SUPT + (size_t)4*5*64*128;   // [300][28][64]
constexpr size_t OF_ROWV = OF_QT   + (size_t)300*28*64;    // (dead rowv space)
constexpr size_t OF_UKEY = OF_ROWV;                        // [4][2500] u64 keys
constexpr size_t OF_SKEY = OF_ROWV + 20000;                // [4][625]  u64 keys
constexpr size_t OF_CBQ  = OF_ROWV + 25000;                // [300] int (unused, zeroed)
constexpr size_t OF_CVI  = OF_ROWV + (size_t)2*4*5*8*2500; // (dead)
constexpr size_t OF_CMP  = OF_CVI  + (size_t)4*5*125*20*2; // [4][5][2500] i
constexpr size_t OF_CNT  = OF_CMP  + (size_t)4*5*2500;     // [20] i
constexpr size_t OF_UNEAR= OF_CNT  + 20;                   // (dead)
constexpr size_t OF_SNEAR= OF_UNEAR+ 10000;                // (dead)
constexpr size_t OF_BV   = OF_SNEAR+ 2500;                 // [300][5][25] f
constexpr size_t OF_BP   = OF_BV   + 37500;                // [300][5][25] i
constexpr size_t OF_AMX  = OF_BP   + 37500;                // [300][3200] u8

typedef __attribute__((ext_vector_type(4)))  float f4s;
typedef __attribute__((ext_vector_type(16))) float f16s;

__device__ __forceinline__ unsigned long long pack_key(float v, int idx) {
    unsigned int e = __float_as_uint(v);
    e ^= (e >> 31) ? 0xFFFFFFFFu : 0x80000000u;   // order-isomorphic f32->u32
    return ((unsigned long long)e << 32) | (unsigned int)~idx;  // tie -> min idx
}

// ============================================================
// Kernel A: L2-normalize (r9 verbatim, HW-passed) + zero out/keys.
// ============================================================
__global__ __launch_bounds__(256) void knorm(
    const float* __restrict__ sup, const float* __restrict__ qry,
    const float* __restrict__ unl, float* __restrict__ ws,
    float* __restrict__ out)
{
    float* unl_n = ws + OF_UNL;
    float* sup_n = ws + OF_SUP;
    float* supT  = ws + OF_SUPT;
    float* qt    = ws + OF_QT;

    int tid = threadIdx.x;
    int lane = tid & 63, wv = tid >> 6;
    int gid = blockIdx.x * 256 + tid;

    if (gid == 0) *out = 0.f;
    if (gid < 25300) ((unsigned int*)(ws + OF_UKEY))[gid] = 0u;  // keys + cnt slot

    int unit = blockIdx.x * 4 + wv;      // 0..799

    __shared__ float ls[4][1600];
    __shared__ float scl[4][32];

    const float* src;
    float* dstT; float* dst2 = nullptr; int dst2_shot = 0; bool isq = false;

    if (unit < 400) {
        int b = unit / 100, u = unit % 100;
        src  = unl + (size_t)unit * 1600;
        dstT = unl_n + ((size_t)(b * 2500 + u * 25)) * 64;
    } else if (unit < 500) {
        int idx2 = unit - 400;
        int b = idx2 / 25, r = idx2 % 25;
        int w = r / 5, shot = r % 5;
        src  = sup + (size_t)(b * 25 + r) * 1600;
        dstT = sup_n + ((size_t)(b * 625 + w * 125 + shot * 25)) * 64;
        dst2 = supT + ((size_t)(b * 5 + w) * 64) * 128;
        dst2_shot = shot * 25;
    } else {
        int bq = unit - 500;
        src  = qry + (size_t)bq * 1600;
        dstT = qt + (size_t)bq * 1792;
        isq = true;
    }

    const float4* s4 = (const float4*)src;
#pragma unroll
    for (int k = 0; k < 7; ++k) {
        int idx = k * 64 + lane;
        if (idx < 400) *(float4*)&ls[wv][idx * 4] = s4[idx];
    }
    __syncthreads();

    if (lane < 25) {
        int hw = lane;
        float p[16];
#pragma unroll
        for (int sub = 0; sub < 16; ++sub) {
            float s = 0.f;
#pragma unroll
            for (int j = 0; j < 4; ++j) {
                float v = ls[wv][(sub * 4 + j) * 25 + hw];
                s += v * v;
            }
            p[sub] = s;
        }
#pragma unroll
        for (int st = 1; st < 16; st <<= 1)
#pragma unroll
            for (int i = 0; i < 16; i += 2 * st)
                p[i] = p[i] + p[i + st];
        scl[wv][hw] = 1.f / fmaxf(sqrtf(p[0]), 1e-12f);
    }
    __syncthreads();

    float4* d4 = (float4*)dstT;
#pragma unroll
    for (int k = 0; k < 7; ++k) {
        int idx = k * 64 + lane;
        if (idx < 400) {
            int f = idx * 4;
            int r_ = f >> 6;
            int c0 = f & 63;
            float m = scl[wv][r_];
            float4 o;
            o.x = ls[wv][ c0      * 25 + r_] * m;
            o.y = ls[wv][(c0 + 1) * 25 + r_] * m;
            o.z = ls[wv][(c0 + 2) * 25 + r_] * m;
            o.w = ls[wv][(c0 + 3) * 25 + r_] * m;
            d4[idx] = o;
        }
    }
    if (isq && lane < 48) d4[400 + lane] = make_float4(0.f, 0.f, 0.f, 0.f);
    if (dst2) {
#pragma unroll
        for (int k = 0; k < 25; ++k) {
            int idx = k * 64 + lane;
            int c = idx / 25, hw2 = idx % 25;
            dst2[(size_t)c * 128 + dst2_shot + hw2] = ls[wv][idx] * scl[wv][hw2];
        }
    }
}

// ============================================================
// Kernel B: u2s pass (r9 verbatim, HW-passed): argmax partials via
// atomicMax on packed u64 keys; kmerge eliminated. The atomics are
// per-line global_atomic ops - NO cache-maintenance cost (unlike
// the r9 kc1 threadfence, which was an agent-scope L2 writeback).
// ============================================================
#define KB2(C) { \
    f16s s0, s1; \
    asm volatile("s_load_dwordx16 %0, %[b], %c[o0]\n\t" \
                 "s_load_dwordx16 %1, %[b], %c[o1]\n\t" \
                 "s_waitcnt lgkmcnt(0)" \
                 : "=s"(s0), "=s"(s1) \
                 : [b]"s"(sbp), [o0]"i"((C)*512), [o1]"i"((C)*512+512)); \
    float2 uv = *(const float2*)&uls[ml * 66 + (C)]; \
    acc[0]  = fmaf(uv.x, s0[0],  fmaf(uv.y, s1[0],  acc[0])); \
    acc[1]  = fmaf(uv.x, s0[1],  fmaf(uv.y, s1[1],  acc[1])); \
    acc[2]  = fmaf(uv.x, s0[2],  fmaf(uv.y, s1[2],  acc[2])); \
    acc[3]  = fmaf(uv.x, s0[3],  fmaf(uv.y, s1[3],  acc[3])); \
    acc[4]  = fmaf(uv.x, s0[4],  fmaf(uv.y, s1[4],  acc[4])); \
    acc[5]  = fmaf(uv.x, s0[5],  fmaf(uv.y, s1[5],  acc[5])); \
    acc[6]  = fmaf(uv.x, s0[6],  fmaf(uv.y, s1[6],  acc[6])); \
    acc[7]  = fmaf(uv.x, s0[7],  fmaf(uv.y, s1[7],  acc[7])); \
    acc[8]  = fmaf(uv.x, s0[8],  fmaf(uv.y, s1[8],  acc[8])); \
    acc[9]  = fmaf(uv.x, s0[9],  fmaf(uv.y, s1[9],  acc[9])); \
    acc[10] = fmaf(uv.x, s0[10], fmaf(uv.y, s1[10], acc[10])); \
    acc[11] = fmaf(uv.x, s0[11], fmaf(uv.y, s1[11], acc[11])); \
    acc[12] = fmaf(uv.x, s0[12], fmaf(uv.y, s1[12], acc[12])); \
    acc[13] = fmaf(uv.x, s0[13], fmaf(uv.y, s1[13], acc[13])); \
    acc[14] = fmaf(uv.x, s0[14], fmaf(uv.y, s1[14], acc[14])); \
    acc[15] = fmaf(uv.x, s0[15], fmaf(uv.y, s1[15], acc[15])); }
#define KB8(C) KB2(C) KB2((C)+2) KB2((C)+4) KB2((C)+6)

__global__ __launch_bounds__(256) void kb(
    const float* __restrict__ unl_n, const float* __restrict__ supT,
    unsigned long long* __restrict__ ukey, unsigned long long* __restrict__ skey)
{
    int bid = blockIdx.x;
    int nc = bid & 3;
    int mb = (bid >> 2) % 20;
    int bw = bid / 80;               // b*5+w
    int b  = bw / 5;
    int w  = bw % 5;
    int tid = threadIdx.x;
    int lane = tid & 63, wv = tid >> 6;

    __shared__ float uls[128 * 66];
    __shared__ float sv_[4][32];
    __shared__ int   si_[4][32];

    int m0 = mb * 128;
    int n0 = nc * 32;

    for (int i = tid; i < 128 * 16; i += 256) {
        int row = i >> 4, c4 = (i & 15) * 4;
        int m = m0 + row;
        float4 x = make_float4(0.f, 0.f, 0.f, 0.f);
        if (m < 2500) x = *(const float4*)(unl_n + ((size_t)(b * 2500 + m)) * 64 + c4);
        *(float2*)&uls[row * 66 + c4]     = make_float2(x.x, x.y);
        *(float2*)&uls[row * 66 + c4 + 2] = make_float2(x.z, x.w);
    }
    __syncthreads();

    int ml = tid & 127;
    int m  = m0 + ml;
    int nh = tid >> 7;
    int nbase = nh * 16;
    int nbu = __builtin_amdgcn_readfirstlane(nbase);
    int nn_total = (125 - n0) < 32 ? (125 - n0) : 32;
    const float* sbp = supT + ((size_t)bw * 64) * 128 + n0 + nbu;

    float acc[16];
#pragma unroll
    for (int j = 0; j < 16; ++j) acc[j] = 0.f;

    KB8(0)  KB8(8)  KB8(16) KB8(24)
    KB8(32) KB8(40) KB8(48) KB8(56)

    // row-side running argmax -> atomic key
    int nnloc = nn_total - nbase;
    nnloc = nnloc < 0 ? 0 : (nnloc > 16 ? 16 : nnloc);
    float rbv = NEGINF; int rbi = 0;
    for (int j = 0; j < nnloc; ++j)
        if (acc[j] > rbv) { rbv = acc[j]; rbi = n0 + nbase + j; }
    if (m < 2500)
        atomicMax(ukey + (b * 2500 + m), pack_key(rbv, w * 125 + rbi));

    // col-side: wave max + ballot/ffs min-m tie-break -> atomic key
#pragma unroll
    for (int j = 0; j < 16; ++j) {
        float v = (m < 2500 && (nbase + j) < nn_total) ? acc[j] : NEGINF;
        float vm = v;
#pragma unroll
        for (int s2 = 1; s2 < 64; s2 <<= 1) vm = fmaxf(vm, __shfl_xor(vm, s2));
        unsigned long long msk = __ballot(v == vm);
        int first = __ffsll((unsigned long long)msk) - 1;
        if (lane == 0) { sv_[wv][nbase + j] = vm; si_[wv][nbase + j] = m0 + (wv & 1) * 64 + first; }
    }
    __syncthreads();
    if (tid < nn_total) {
        int w0 = (tid < 16) ? 0 : 2;
        float v = sv_[w0][tid];     int vi = si_[w0][tid];
        float v2 = sv_[w0 + 1][tid]; int i2 = si_[w0 + 1][tid];
        if (v2 > v || (v2 == v && i2 < vi)) { v = v2; vi = i2; }
        atomicMax(skey + (bw * 125 + n0 + tid), pack_key(v, vi));
    }
}

// ============================================================
// Kernel P: mutual-NN mask + stable compaction (r9 verbatim).
// ============================================================
__global__ __launch_bounds__(256) void kcmp(
    const unsigned long long* __restrict__ ukey,
    const unsigned long long* __restrict__ skey,
    int* __restrict__ cmp, int* __restrict__ cntg)
{
    int p = blockIdx.x;
    int b = p / 5, way = p % 5;
    int tid = threadIdx.x, lane = tid & 63, wv = tid >> 6;
    __shared__ unsigned long long masks[40];
    __shared__ int base[40];

    for (int ch = wv; ch < 40; ch += 4) {
        int m = ch * 64 + lane;
        bool ok = false;
        if (m < 2500) {
            int un = (int)(~(unsigned int)ukey[b * 2500 + m]);   // w*125+n
            ok = (un / 125 == way) &&
                 ((int)(~(unsigned int)skey[b * 625 + un]) == m);
        }
        unsigned long long msk = __ballot(ok ? 1 : 0);
        if (lane == 0) masks[ch] = msk;
    }
    __syncthreads();
    if (tid == 0) {
        int s = 0;
        for (int ch = 0; ch < 40; ++ch) { base[ch] = s; s += __popcll(masks[ch]); }
        cntg[p] = s;
    }
    __syncthreads();
    for (int ch = wv; ch < 40; ch += 4) {
        unsigned long long msk = masks[ch];
        if ((msk >> lane) & 1ull) {
            int pre = __popcll(msk & ((1ull << lane) - 1ull));
            cmp[(size_t)p * 2500 + base[ch] + pre] = ch * 64 + lane;
        }
    }
}

// ============================================================
// Kernel C1: REVERTED to the r5/r8-proven 44.4us body. The r9 fused
// kce (per-block __threadfence = agent-scope L2 writeback x1500
// blocks) cost 150us of stall (VALUBusy 44->11%) - removed.
// ============================================================
#define QLOAD(CG, Q0,Q1,Q2,Q3,Q4,Q5,Q6) \
  asm volatile( \
    "s_load_dwordx4 %0, %[b], %c[o0]\n\t" \
    "s_load_dwordx4 %1, %[b], %c[o1]\n\t" \
    "s_load_dwordx4 %2, %[b], %c[o2]\n\t" \
    "s_load_dwordx4 %3, %[b], %c[o3]\n\t" \
    "s_load_dwordx4 %4, %[b], %c[o4]\n\t" \
    "s_load_dwordx4 %5, %[b], %c[o5]\n\t" \
    "s_load_dwordx4 %6, %[b], %c[o6]\n\t" \
    "s_waitcnt lgkmcnt(0)" \
    : "=s"(Q0), "=s"(Q1), "=s"(Q2), "=s"(Q3), "=s"(Q4), "=s"(Q5), "=s"(Q6) \
    : [b]"s"(qbp), \
      [o0]"i"((CG)*16 + 0*256), [o1]"i"((CG)*16 + 1*256), \
      [o2]"i"((CG)*16 + 2*256), [o3]"i"((CG)*16 + 3*256), \
      [o4]"i"((CG)*16 + 4*256), [o5]"i"((CG)*16 + 5*256), \
      [o6]"i"((CG)*16 + 6*256))

#define CGSTEP(CG) { \
    f4s q0,q1,q2,q3,q4,q5,q6; \
    QLOAD(CG, q0,q1,q2,q3,q4,q5,q6); \
    float4 cl = *(const float4*)&cls[lane * 68 + (CG) * 4]; \
    acc[0]=fmaf(q0.x,cl.x,fmaf(q0.y,cl.y,fmaf(q0.z,cl.z,fmaf(q0.w,cl.w,acc[0])))); \
    acc[1]=fmaf(q1.x,cl.x,fmaf(q1.y,cl.y,fmaf(q1.z,cl.z,fmaf(q1.w,cl.w,acc[1])))); \
    acc[2]=fmaf(q2.x,cl.x,fmaf(q2.y,cl.y,fmaf(q2.z,cl.z,fmaf(q2.w,cl.w,acc[2])))); \
    acc[3]=fmaf(q3.x,cl.x,fmaf(q3.y,cl.y,fmaf(q3.z,cl.z,fmaf(q3.w,cl.w,acc[3])))); \
    acc[4]=fmaf(q4.x,cl.x,fmaf(q4.y,cl.y,fmaf(q4.z,cl.z,fmaf(q4.w,cl.w,acc[4])))); \
    acc[5]=fmaf(q5.x,cl.x,fmaf(q5.y,cl.y,fmaf(q5.z,cl.z,fmaf(q5.w,cl.w,acc[5])))); \
    acc[6]=fmaf(q6.x,cl.x,fmaf(q6.y,cl.y,fmaf(q6.z,cl.z,fmaf(q6.w,cl.w,acc[6])))); }

__global__ __launch_bounds__(256) void kc1(
    const float* __restrict__ qt, const float* __restrict__ sup_n,
    const float* __restrict__ unl_n, const int* __restrict__ cmp,
    const int* __restrict__ cntg,
    float* __restrict__ bvg, int* __restrict__ bpg,
    unsigned char* __restrict__ amaxg)
{
    int bid = blockIdx.x;
    int w = bid % 5, bq = bid / 5;
    int b = bq / 75;
    int tid = threadIdx.x;
    int lane = tid & 63;
    int wvu = __builtin_amdgcn_readfirstlane(tid >> 6);
    int pbw = b * 5 + w;

    int L = 0;
#pragma unroll
    for (int i = 0; i < 20; ++i) { int v = cntg[i]; L = L > v ? L : v; }
    int cntw = 0, wb = 0;
#pragma unroll
    for (int w2 = 0; w2 < 5; ++w2) {
        int c2 = cntg[b * 5 + w2];
        if (w2 < w) wb += 125 + c2;
        if (w2 == w) cntw = c2;
    }
    int cw = 125 + cntw;             // 125..250

    __shared__ float cls[64 * 68];
    __shared__ float amxv[4][64];
    __shared__ int   amxg_[4][64];
    __shared__ float redv[25];
    __shared__ int   redn[25];

    const float* qbp = qt + ((size_t)bq * 28 + wvu * 7) * 64;

    float rv[7]; int rn[7];
#pragma unroll
    for (int j = 0; j < 7; ++j) { rv[j] = NEGINF; rn[j] = 0x7fffffff; }

    int nb = (cw + 63) >> 6;

    for (int b4 = 0; b4 < nb; ++b4) {
        if (b4 > 0 && tid < 64) {
            int n = (b4 - 1) * 64 + tid;
            if (n < cw) {
                float v = amxv[0][tid]; int g = amxg_[0][tid];
#pragma unroll
                for (int g2 = 1; g2 < 4; ++g2)
                    if (amxv[g2][tid] > v) { v = amxv[g2][tid]; g = amxg_[g2][tid]; }
                amaxg[(size_t)bq * 3200 + (wb + n)] = (unsigned char)g;
            }
        }
#pragma unroll
        for (int k = 0; k < 4; ++k) {
            int i = tid + k * 256;
            int row = i >> 4, ch = i & 15;
            int n = b4 * 64 + row;
            float4 x = make_float4(0.f, 0.f, 0.f, 0.f);
            if (n < cw) {
                const float* cp;
                if (n < 125) cp = sup_n + (((size_t)pbw) * 125 + n) * 64;
                else { int m = cmp[((size_t)pbw) * 2500 + (n - 125)];
                       cp = unl_n + ((size_t)(b * 2500 + m)) * 64; }
                x = *(const float4*)(cp + ch * 4);
            }
            *(float4*)&cls[row * 68 + ch * 4] = x;
        }
        __syncthreads();

        float acc[7];
#pragma unroll
        for (int j = 0; j < 7; ++j) acc[j] = 0.f;

        CGSTEP(0);  CGSTEP(1);  CGSTEP(2);  CGSTEP(3);
        CGSTEP(4);  CGSTEP(5);  CGSTEP(6);  CGSTEP(7);
        CGSTEP(8);  CGSTEP(9);  CGSTEP(10); CGSTEP(11);
        CGSTEP(12); CGSTEP(13); CGSTEP(14); CGSTEP(15);

        bool colvalid = (b4 * 64 + lane) < cw;
        float cmax = NEGINF; int cam = 0;
#pragma unroll
        for (int j = 0; j < 7; ++j) {
            int mq = wvu * 7 + j;
            float s = (acc[j] + 1.0f) * 0.5f;
            float sm = (colvalid && mq < 25) ? s : NEGINF;
            if (sm > cmax) { cmax = sm; cam = mq; }
            float vm = sm;
#pragma unroll
            for (int t = 1; t < 64; t <<= 1) vm = fmaxf(vm, __shfl_xor(vm, t));
            unsigned long long msk = __ballot(sm == vm);
            int first = __ffsll(msk) - 1;
            if (vm > rv[j]) { rv[j] = vm; rn[j] = b4 * 64 + first; }
        }
        amxv[wvu][lane] = cmax; amxg_[wvu][lane] = cam;
        __syncthreads();
    }

    if (tid < 64) {
        int n = (nb - 1) * 64 + tid;
        if (n < cw) {
            float v = amxv[0][tid]; int g = amxg_[0][tid];
#pragma unroll
            for (int g2 = 1; g2 < 4; ++g2)
                if (amxv[g2][tid] > v) { v = amxv[g2][tid]; g = amxg_[g2][tid]; }
            amaxg[(size_t)bq * 3200 + (wb + n)] = (unsigned char)g;
        }
    }
    if (lane == 0) {
#pragma unroll
        for (int j = 0; j < 7; ++j) {
            int mq = wvu * 7 + j;
            if (mq < 25) { redv[mq] = rv[j]; redn[mq] = rn[j]; }
        }
    }
    __syncthreads();

    if (tid < 25) {
        float v = redv[tid]; int nn = redn[tid];
        int p = ((w * 2625 + nn) << 12) | (wb + nn);
        if (L > cntw) {
            int pp = ((w * 2625 + 125 + cntw) << 12) | 0xFFF;
            if (0.5f > v || (0.5f == v && pp < p)) { v = 0.5f; p = pp; }
        }
        size_t o = ((size_t)bq * 5 + w) * 25 + tid;
        bvg[o] = v; bpg[o] = p;
    }
}

// ============================================================
// Kernel CE: merge 5 way-partials per (bq,mq), mutual mask, row loss,
// atomicAdd into d_out. 300 blocks x 64. (r5 verbatim, proven)
// ============================================================
__global__ __launch_bounds__(64) void kce(
    const float* __restrict__ bvg, const int* __restrict__ bpg,
    const unsigned char* __restrict__ amaxg, const int* __restrict__ qy,
    float* __restrict__ out)
{
    int bq = blockIdx.x;
    int tid = threadIdx.x;
    __shared__ float qmask[25];
    __shared__ float lg[5];
    if (tid < 25) {
        float v = NEGINF; int p = 0x7fffffff;
#pragma unroll
        for (int w = 0; w < 5; ++w) {
            size_t o = ((size_t)bq * 5 + w) * 25 + tid;
            float v2 = bvg[o]; int p2 = bpg[o];
            if (v2 > v || (v2 == v && p2 < p)) { v = v2; p = p2; }
        }
        int pos = p & 0xFFF;
        int g = (pos == 0xFFF) ? 0 : (int)amaxg[(size_t)bq * 3200 + pos];
        qmask[tid] = (g == tid) ? 1.0f : 0.0f;
    }
    __syncthreads();
    if (tid < 5) {
        float s = 0.f;
#pragma unroll
        for (int mq = 0; mq < 25; ++mq)
            s += bvg[((size_t)bq * 5 + tid) * 25 + mq] * qmask[mq];
        lg[tid] = s;
    }
    __syncthreads();
    if (tid == 0) {
        int y = qy[bq];
        float mx = lg[0];
#pragma unroll
        for (int w = 1; w < 5; ++w) mx = fmaxf(mx, lg[w]);
        float se = 0.f;
#pragma unroll
        for (int w = 0; w < 5; ++w) se += expf(lg[w] - mx);
        float loss = -(lg[y] - mx - logf(se));
        atomicAdd(out, loss * (1.0f / 300.0f));
    }
}

// ============================================================
extern "C" void kernel_launch(void* const* d_in, const int* in_sizes, int n_in,
                              void* d_out, int out_size, void* d_ws, size_t ws_size,
                              hipStream_t stream)
{
    const float* sup = (const float*)d_in[0];
    const float* qry = (const float*)d_in[2];
    const int*   qy  = (const int*)d_in[3];
    const float* unl = (const float*)d_in[4];

    float* ws    = (float*)d_ws;
    float* unl_n = ws + OF_UNL;
    float* sup_n = ws + OF_SUP;
    float* supT  = ws + OF_SUPT;
    float* qt    = ws + OF_QT;
    unsigned long long* ukey = (unsigned long long*)(ws + OF_UKEY);
    unsigned long long* skey = (unsigned long long*)(ws + OF_SKEY);
    int*   cmp   = (int*)(ws + OF_CMP);
    int*   cntg  = (int*)(ws + OF_CNT);
    float* bvg   = ws + OF_BV;
    int*   bpg   = (int*)(ws + OF_BP);
    unsigned char* amaxg = (unsigned char*)(ws + OF_AMX);

    hipLaunchKernelGGL(knorm, dim3(200), dim3(256), 0, stream,
                       sup, qry, unl, ws, (float*)d_out);
    hipLaunchKernelGGL(kb, dim3(1600), dim3(256), 0, stream,
                       unl_n, supT, ukey, skey);
    hipLaunchKernelGGL(kcmp, dim3(20), dim3(256), 0, stream,
                       ukey, skey, cmp, cntg);
    hipLaunchKernelGGL(kc1, dim3(1500), dim3(256), 0, stream,
                       qt, sup_n, unl_n, cmp, cntg, bvg, bpg, amaxg);
    hipLaunchKernelGGL(kce, dim3(300), dim3(64), 0, stream,
                       bvg, bpg, amaxg, qy, (float*)d_out);
}

// Round 12
// 154.591 us; speedup vs baseline: 3.2805x; 1.0157x over previous
//
#include <hip/hip_runtime.h>

#define NEGINF (-1e30f)

// ---------------- problem constants ----------------
// b=4, c=64, h=w=5, q=75, u=100, N_WAY=5, K_SHOT=5
// M_s = 125 (per way), M_u = 2500, M_q = 25, M_tot = 2625
// ---------------- workspace layout (float units) ----------------
// r10 layout (HW-passed, 157.0us). cntbq (zeroed by knorm) now used
// by the fused kc1+kce last-block pattern.
constexpr size_t OF_UNL  = 0;                              // [4][2500][64]
constexpr size_t OF_SUP  = OF_UNL  + (size_t)4*2500*64;    // [4][5][125][64]
constexpr size_t OF_SUPT = OF_SUP  + (size_t)4*5*125*64;   // [4][5][64][128]
constexpr size_t OF_QT   = OF_SUPT + (size_t)4*5*64*128;   // [300][28][64]
constexpr size_t OF_ROWV = OF_QT   + (size_t)300*28*64;    // (dead rowv space)
constexpr size_t OF_UKEY = OF_ROWV;                        // [4][2500] u64 keys
constexpr size_t OF_SKEY = OF_ROWV + 20000;                // [4][625]  u64 keys
constexpr size_t OF_CBQ  = OF_ROWV + 25000;                // [300] int (zeroed by knorm)
constexpr size_t OF_CVI  = OF_ROWV + (size_t)2*4*5*8*2500; // (dead)
constexpr size_t OF_CMP  = OF_CVI  + (size_t)4*5*125*20*2; // [4][5][2500] i
constexpr size_t OF_CNT  = OF_CMP  + (size_t)4*5*2500;     // [20] i
constexpr size_t OF_UNEAR= OF_CNT  + 20;                   // (dead)
constexpr size_t OF_SNEAR= OF_UNEAR+ 10000;                // (dead)
constexpr size_t OF_BV   = OF_SNEAR+ 2500;                 // [300][5][25] f
constexpr size_t OF_BP   = OF_BV   + 37500;                // [300][5][25] i
constexpr size_t OF_AMX  = OF_BP   + 37500;                // [300][3200] u8

typedef __attribute__((ext_vector_type(4)))  float f4s;
typedef __attribute__((ext_vector_type(16))) float f16s;

__device__ __forceinline__ unsigned long long pack_key(float v, int idx) {
    unsigned int e = __float_as_uint(v);
    e ^= (e >> 31) ? 0xFFFFFFFFu : 0x80000000u;   // order-isomorphic f32->u32
    return ((unsigned long long)e << 32) | (unsigned int)~idx;  // tie -> min idx
}

// ============================================================
// Kernel A: L2-normalize (r9/r10 verbatim, HW-passed) + zero out,
// argmax keys, and the cntbq counter.
// ============================================================
__global__ __launch_bounds__(256) void knorm(
    const float* __restrict__ sup, const float* __restrict__ qry,
    const float* __restrict__ unl, float* __restrict__ ws,
    float* __restrict__ out)
{
    float* unl_n = ws + OF_UNL;
    float* sup_n = ws + OF_SUP;
    float* supT  = ws + OF_SUPT;
    float* qt    = ws + OF_QT;

    int tid = threadIdx.x;
    int lane = tid & 63, wv = tid >> 6;
    int gid = blockIdx.x * 256 + tid;

    if (gid == 0) *out = 0.f;
    if (gid < 25300) ((unsigned int*)(ws + OF_UKEY))[gid] = 0u;  // keys + cntbq

    int unit = blockIdx.x * 4 + wv;      // 0..799

    __shared__ float ls[4][1600];
    __shared__ float scl[4][32];

    const float* src;
    float* dstT; float* dst2 = nullptr; int dst2_shot = 0; bool isq = false;

    if (unit < 400) {
        int b = unit / 100, u = unit % 100;
        src  = unl + (size_t)unit * 1600;
        dstT = unl_n + ((size_t)(b * 2500 + u * 25)) * 64;
    } else if (unit < 500) {
        int idx2 = unit - 400;
        int b = idx2 / 25, r = idx2 % 25;
        int w = r / 5, shot = r % 5;
        src  = sup + (size_t)(b * 25 + r) * 1600;
        dstT = sup_n + ((size_t)(b * 625 + w * 125 + shot * 25)) * 64;
        dst2 = supT + ((size_t)(b * 5 + w) * 64) * 128;
        dst2_shot = shot * 25;
    } else {
        int bq = unit - 500;
        src  = qry + (size_t)bq * 1600;
        dstT = qt + (size_t)bq * 1792;
        isq = true;
    }

    const float4* s4 = (const float4*)src;
#pragma unroll
    for (int k = 0; k < 7; ++k) {
        int idx = k * 64 + lane;
        if (idx < 400) *(float4*)&ls[wv][idx * 4] = s4[idx];
    }
    __syncthreads();

    if (lane < 25) {
        int hw = lane;
        float p[16];
#pragma unroll
        for (int sub = 0; sub < 16; ++sub) {
            float s = 0.f;
#pragma unroll
            for (int j = 0; j < 4; ++j) {
                float v = ls[wv][(sub * 4 + j) * 25 + hw];
                s += v * v;
            }
            p[sub] = s;
        }
#pragma unroll
        for (int st = 1; st < 16; st <<= 1)
#pragma unroll
            for (int i = 0; i < 16; i += 2 * st)
                p[i] = p[i] + p[i + st];
        scl[wv][hw] = 1.f / fmaxf(sqrtf(p[0]), 1e-12f);
    }
    __syncthreads();

    float4* d4 = (float4*)dstT;
#pragma unroll
    for (int k = 0; k < 7; ++k) {
        int idx = k * 64 + lane;
        if (idx < 400) {
            int f = idx * 4;
            int r_ = f >> 6;
            int c0 = f & 63;
            float m = scl[wv][r_];
            float4 o;
            o.x = ls[wv][ c0      * 25 + r_] * m;
            o.y = ls[wv][(c0 + 1) * 25 + r_] * m;
            o.z = ls[wv][(c0 + 2) * 25 + r_] * m;
            o.w = ls[wv][(c0 + 3) * 25 + r_] * m;
            d4[idx] = o;
        }
    }
    if (isq && lane < 48) d4[400 + lane] = make_float4(0.f, 0.f, 0.f, 0.f);
    if (dst2) {
#pragma unroll
        for (int k = 0; k < 25; ++k) {
            int idx = k * 64 + lane;
            int c = idx / 25, hw2 = idx % 25;
            dst2[(size_t)c * 128 + dst2_shot + hw2] = ls[wv][idx] * scl[wv][hw2];
        }
    }
}

// ============================================================
// Kernel B: u2s pass (r9/r10 verbatim, HW-passed).
// ============================================================
#define KB2(C) { \
    f16s s0, s1; \
    asm volatile("s_load_dwordx16 %0, %[b], %c[o0]\n\t" \
                 "s_load_dwordx16 %1, %[b], %c[o1]\n\t" \
                 "s_waitcnt lgkmcnt(0)" \
                 : "=s"(s0), "=s"(s1) \
                 : [b]"s"(sbp), [o0]"i"((C)*512), [o1]"i"((C)*512+512)); \
    float2 uv = *(const float2*)&uls[ml * 66 + (C)]; \
    acc[0]  = fmaf(uv.x, s0[0],  fmaf(uv.y, s1[0],  acc[0])); \
    acc[1]  = fmaf(uv.x, s0[1],  fmaf(uv.y, s1[1],  acc[1])); \
    acc[2]  = fmaf(uv.x, s0[2],  fmaf(uv.y, s1[2],  acc[2])); \
    acc[3]  = fmaf(uv.x, s0[3],  fmaf(uv.y, s1[3],  acc[3])); \
    acc[4]  = fmaf(uv.x, s0[4],  fmaf(uv.y, s1[4],  acc[4])); \
    acc[5]  = fmaf(uv.x, s0[5],  fmaf(uv.y, s1[5],  acc[5])); \
    acc[6]  = fmaf(uv.x, s0[6],  fmaf(uv.y, s1[6],  acc[6])); \
    acc[7]  = fmaf(uv.x, s0[7],  fmaf(uv.y, s1[7],  acc[7])); \
    acc[8]  = fmaf(uv.x, s0[8],  fmaf(uv.y, s1[8],  acc[8])); \
    acc[9]  = fmaf(uv.x, s0[9],  fmaf(uv.y, s1[9],  acc[9])); \
    acc[10] = fmaf(uv.x, s0[10], fmaf(uv.y, s1[10], acc[10])); \
    acc[11] = fmaf(uv.x, s0[11], fmaf(uv.y, s1[11], acc[11])); \
    acc[12] = fmaf(uv.x, s0[12], fmaf(uv.y, s1[12], acc[12])); \
    acc[13] = fmaf(uv.x, s0[13], fmaf(uv.y, s1[13], acc[13])); \
    acc[14] = fmaf(uv.x, s0[14], fmaf(uv.y, s1[14], acc[14])); \
    acc[15] = fmaf(uv.x, s0[15], fmaf(uv.y, s1[15], acc[15])); }
#define KB8(C) KB2(C) KB2((C)+2) KB2((C)+4) KB2((C)+6)

__global__ __launch_bounds__(256) void kb(
    const float* __restrict__ unl_n, const float* __restrict__ supT,
    unsigned long long* __restrict__ ukey, unsigned long long* __restrict__ skey)
{
    int bid = blockIdx.x;
    int nc = bid & 3;
    int mb = (bid >> 2) % 20;
    int bw = bid / 80;               // b*5+w
    int b  = bw / 5;
    int w  = bw % 5;
    int tid = threadIdx.x;
    int lane = tid & 63, wv = tid >> 6;

    __shared__ float uls[128 * 66];
    __shared__ float sv_[4][32];
    __shared__ int   si_[4][32];

    int m0 = mb * 128;
    int n0 = nc * 32;

    for (int i = tid; i < 128 * 16; i += 256) {
        int row = i >> 4, c4 = (i & 15) * 4;
        int m = m0 + row;
        float4 x = make_float4(0.f, 0.f, 0.f, 0.f);
        if (m < 2500) x = *(const float4*)(unl_n + ((size_t)(b * 2500 + m)) * 64 + c4);
        *(float2*)&uls[row * 66 + c4]     = make_float2(x.x, x.y);
        *(float2*)&uls[row * 66 + c4 + 2] = make_float2(x.z, x.w);
    }
    __syncthreads();

    int ml = tid & 127;
    int m  = m0 + ml;
    int nh = tid >> 7;
    int nbase = nh * 16;
    int nbu = __builtin_amdgcn_readfirstlane(nbase);
    int nn_total = (125 - n0) < 32 ? (125 - n0) : 32;
    const float* sbp = supT + ((size_t)bw * 64) * 128 + n0 + nbu;

    float acc[16];
#pragma unroll
    for (int j = 0; j < 16; ++j) acc[j] = 0.f;

    KB8(0)  KB8(8)  KB8(16) KB8(24)
    KB8(32) KB8(40) KB8(48) KB8(56)

    // row-side running argmax -> atomic key
    int nnloc = nn_total - nbase;
    nnloc = nnloc < 0 ? 0 : (nnloc > 16 ? 16 : nnloc);
    float rbv = NEGINF; int rbi = 0;
    for (int j = 0; j < nnloc; ++j)
        if (acc[j] > rbv) { rbv = acc[j]; rbi = n0 + nbase + j; }
    if (m < 2500)
        atomicMax(ukey + (b * 2500 + m), pack_key(rbv, w * 125 + rbi));

    // col-side: wave max + ballot/ffs min-m tie-break -> atomic key
#pragma unroll
    for (int j = 0; j < 16; ++j) {
        float v = (m < 2500 && (nbase + j) < nn_total) ? acc[j] : NEGINF;
        float vm = v;
#pragma unroll
        for (int s2 = 1; s2 < 64; s2 <<= 1) vm = fmaxf(vm, __shfl_xor(vm, s2));
        unsigned long long msk = __ballot(v == vm);
        int first = __ffsll((unsigned long long)msk) - 1;
        if (lane == 0) { sv_[wv][nbase + j] = vm; si_[wv][nbase + j] = m0 + (wv & 1) * 64 + first; }
    }
    __syncthreads();
    if (tid < nn_total) {
        int w0 = (tid < 16) ? 0 : 2;
        float v = sv_[w0][tid];     int vi = si_[w0][tid];
        float v2 = sv_[w0 + 1][tid]; int i2 = si_[w0 + 1][tid];
        if (v2 > v || (v2 == v && i2 < vi)) { v = v2; vi = i2; }
        atomicMax(skey + (bw * 125 + n0 + tid), pack_key(v, vi));
    }
}

// ============================================================
// Kernel P: mutual-NN mask + stable compaction (r9/r10 verbatim).
// ============================================================
__global__ __launch_bounds__(256) void kcmp(
    const unsigned long long* __restrict__ ukey,
    const unsigned long long* __restrict__ skey,
    int* __restrict__ cmp, int* __restrict__ cntg)
{
    int p = blockIdx.x;
    int b = p / 5, way = p % 5;
    int tid = threadIdx.x, lane = tid & 63, wv = tid >> 6;
    __shared__ unsigned long long masks[40];
    __shared__ int base[40];

    for (int ch = wv; ch < 40; ch += 4) {
        int m = ch * 64 + lane;
        bool ok = false;
        if (m < 2500) {
            int un = (int)(~(unsigned int)ukey[b * 2500 + m]);   // w*125+n
            ok = (un / 125 == way) &&
                 ((int)(~(unsigned int)skey[b * 625 + un]) == m);
        }
        unsigned long long msk = __ballot(ok ? 1 : 0);
        if (lane == 0) masks[ch] = msk;
    }
    __syncthreads();
    if (tid == 0) {
        int s = 0;
        for (int ch = 0; ch < 40; ++ch) { base[ch] = s; s += __popcll(masks[ch]); }
        cntg[p] = s;
    }
    __syncthreads();
    for (int ch = wv; ch < 40; ch += 4) {
        unsigned long long msk = masks[ch];
        if ((msk >> lane) & 1ull) {
            int pre = __popcll(msk & ((1ull << lane) - 1ull));
            cmp[(size_t)p * 2500 + base[ch] + pre] = ch * 64 + lane;
        }
    }
}

// ============================================================
// Kernel C1 (r5/r10-proven body) + fused kce, ATOMICS-ONLY:
// r9's fused kce died on per-block __threadfence (agent-scope L2
// writeback x1500). This version uses ONLY cheap coherent ops:
//  - all global outputs (bvg/bpg/amaxg - all issued by wave 0)
//    become agent-scope relaxed atomic stores (sc1 write-through,
//    per-line, no cache flush);
//  - ordering = s_waitcnt vmcnt(0) in wave 0 (wait own stores
//    reached the coherence point - no cache maintenance), then a
//    relaxed agent fetch_add on cntbq[bq];
//  - the block seeing ret==4 runs the kce body with agent-scope
//    relaxed atomic loads (bypass local L2, read coherence point).
// FP order in the kce body is bit-identical to the r10 kce kernel.
// ============================================================
#define QLOAD(CG, Q0,Q1,Q2,Q3,Q4,Q5,Q6) \
  asm volatile( \
    "s_load_dwordx4 %0, %[b], %c[o0]\n\t" \
    "s_load_dwordx4 %1, %[b], %c[o1]\n\t" \
    "s_load_dwordx4 %2, %[b], %c[o2]\n\t" \
    "s_load_dwordx4 %3, %[b], %c[o3]\n\t" \
    "s_load_dwordx4 %4, %[b], %c[o4]\n\t" \
    "s_load_dwordx4 %5, %[b], %c[o5]\n\t" \
    "s_load_dwordx4 %6, %[b], %c[o6]\n\t" \
    "s_waitcnt lgkmcnt(0)" \
    : "=s"(Q0), "=s"(Q1), "=s"(Q2), "=s"(Q3), "=s"(Q4), "=s"(Q5), "=s"(Q6) \
    : [b]"s"(qbp), \
      [o0]"i"((CG)*16 + 0*256), [o1]"i"((CG)*16 + 1*256), \
      [o2]"i"((CG)*16 + 2*256), [o3]"i"((CG)*16 + 3*256), \
      [o4]"i"((CG)*16 + 4*256), [o5]"i"((CG)*16 + 5*256), \
      [o6]"i"((CG)*16 + 6*256))

#define CGSTEP(CG) { \
    f4s q0,q1,q2,q3,q4,q5,q6; \
    QLOAD(CG, q0,q1,q2,q3,q4,q5,q6); \
    float4 cl = *(const float4*)&cls[lane * 68 + (CG) * 4]; \
    acc[0]=fmaf(q0.x,cl.x,fmaf(q0.y,cl.y,fmaf(q0.z,cl.z,fmaf(q0.w,cl.w,acc[0])))); \
    acc[1]=fmaf(q1.x,cl.x,fmaf(q1.y,cl.y,fmaf(q1.z,cl.z,fmaf(q1.w,cl.w,acc[1])))); \
    acc[2]=fmaf(q2.x,cl.x,fmaf(q2.y,cl.y,fmaf(q2.z,cl.z,fmaf(q2.w,cl.w,acc[2])))); \
    acc[3]=fmaf(q3.x,cl.x,fmaf(q3.y,cl.y,fmaf(q3.z,cl.z,fmaf(q3.w,cl.w,acc[3])))); \
    acc[4]=fmaf(q4.x,cl.x,fmaf(q4.y,cl.y,fmaf(q4.z,cl.z,fmaf(q4.w,cl.w,acc[4])))); \
    acc[5]=fmaf(q5.x,cl.x,fmaf(q5.y,cl.y,fmaf(q5.z,cl.z,fmaf(q5.w,cl.w,acc[5])))); \
    acc[6]=fmaf(q6.x,cl.x,fmaf(q6.y,cl.y,fmaf(q6.z,cl.z,fmaf(q6.w,cl.w,acc[6])))); }

#define ASTORE_F(P, V) __hip_atomic_store((P), (V), __ATOMIC_RELAXED, __HIP_MEMORY_SCOPE_AGENT)
#define ASTORE_I(P, V) __hip_atomic_store((P), (V), __ATOMIC_RELAXED, __HIP_MEMORY_SCOPE_AGENT)
#define ALOAD(P)       __hip_atomic_load((P), __ATOMIC_RELAXED, __HIP_MEMORY_SCOPE_AGENT)

__global__ __launch_bounds__(256) void kc1(
    const float* __restrict__ qt, const float* __restrict__ sup_n,
    const float* __restrict__ unl_n, const int* __restrict__ cmp,
    const int* __restrict__ cntg,
    float* __restrict__ bvg, int* __restrict__ bpg,
    unsigned char* __restrict__ amaxg, int* __restrict__ cntbq,
    const int* __restrict__ qy, float* __restrict__ out)
{
    int bid = blockIdx.x;
    int w = bid % 5, bq = bid / 5;
    int b = bq / 75;
    int tid = threadIdx.x;
    int lane = tid & 63;
    int wvu = __builtin_amdgcn_readfirstlane(tid >> 6);
    int pbw = b * 5 + w;

    int L = 0;
#pragma unroll
    for (int i = 0; i < 20; ++i) { int v = cntg[i]; L = L > v ? L : v; }
    int cntw = 0, wb = 0;
#pragma unroll
    for (int w2 = 0; w2 < 5; ++w2) {
        int c2 = cntg[b * 5 + w2];
        if (w2 < w) wb += 125 + c2;
        if (w2 == w) cntw = c2;
    }
    int cw = 125 + cntw;             // 125..250

    __shared__ float cls[64 * 68];
    __shared__ float amxv[4][64];
    __shared__ int   amxg_[4][64];
    __shared__ float redv[25];
    __shared__ int   redn[25];
    __shared__ int   lastf;
    __shared__ float qmask[25];
    __shared__ float lg[5];

    const float* qbp = qt + ((size_t)bq * 28 + wvu * 7) * 64;

    float rv[7]; int rn[7];
#pragma unroll
    for (int j = 0; j < 7; ++j) { rv[j] = NEGINF; rn[j] = 0x7fffffff; }

    int nb = (cw + 63) >> 6;

    for (int b4 = 0; b4 < nb; ++b4) {
        if (b4 > 0 && tid < 64) {
            int n = (b4 - 1) * 64 + tid;
            if (n < cw) {
                float v = amxv[0][tid]; int g = amxg_[0][tid];
#pragma unroll
                for (int g2 = 1; g2 < 4; ++g2)
                    if (amxv[g2][tid] > v) { v = amxv[g2][tid]; g = amxg_[g2][tid]; }
                ASTORE_I(&amaxg[(size_t)bq * 3200 + (wb + n)], (unsigned char)g);
            }
        }
#pragma unroll
        for (int k = 0; k < 4; ++k) {
            int i = tid + k * 256;
            int row = i >> 4, ch = i & 15;
            int n = b4 * 64 + row;
            float4 x = make_float4(0.f, 0.f, 0.f, 0.f);
            if (n < cw) {
                const float* cp;
                if (n < 125) cp = sup_n + (((size_t)pbw) * 125 + n) * 64;
                else { int m = cmp[((size_t)pbw) * 2500 + (n - 125)];
                       cp = unl_n + ((size_t)(b * 2500 + m)) * 64; }
                x = *(const float4*)(cp + ch * 4);
            }
            *(float4*)&cls[row * 68 + ch * 4] = x;
        }
        __syncthreads();

        float acc[7];
#pragma unroll
        for (int j = 0; j < 7; ++j) acc[j] = 0.f;

        CGSTEP(0);  CGSTEP(1);  CGSTEP(2);  CGSTEP(3);
        CGSTEP(4);  CGSTEP(5);  CGSTEP(6);  CGSTEP(7);
        CGSTEP(8);  CGSTEP(9);  CGSTEP(10); CGSTEP(11);
        CGSTEP(12); CGSTEP(13); CGSTEP(14); CGSTEP(15);

        bool colvalid = (b4 * 64 + lane) < cw;
        float cmax = NEGINF; int cam = 0;
#pragma unroll
        for (int j = 0; j < 7; ++j) {
            int mq = wvu * 7 + j;
            float s = (acc[j] + 1.0f) * 0.5f;
            float sm = (colvalid && mq < 25) ? s : NEGINF;
            if (sm > cmax) { cmax = sm; cam = mq; }
            float vm = sm;
#pragma unroll
            for (int t = 1; t < 64; t <<= 1) vm = fmaxf(vm, __shfl_xor(vm, t));
            unsigned long long msk = __ballot(sm == vm);
            int first = __ffsll(msk) - 1;
            if (vm > rv[j]) { rv[j] = vm; rn[j] = b4 * 64 + first; }
        }
        amxv[wvu][lane] = cmax; amxg_[wvu][lane] = cam;
        __syncthreads();
    }

    if (tid < 64) {
        int n = (nb - 1) * 64 + tid;
        if (n < cw) {
            float v = amxv[0][tid]; int g = amxg_[0][tid];
#pragma unroll
            for (int g2 = 1; g2 < 4; ++g2)
                if (amxv[g2][tid] > v) { v = amxv[g2][tid]; g = amxg_[g2][tid]; }
            ASTORE_I(&amaxg[(size_t)bq * 3200 + (wb + n)], (unsigned char)g);
        }
    }
    if (lane == 0) {
#pragma unroll
        for (int j = 0; j < 7; ++j) {
            int mq = wvu * 7 + j;
            if (mq < 25) { redv[mq] = rv[j]; redn[mq] = rn[j]; }
        }
    }
    __syncthreads();

    if (tid < 25) {
        float v = redv[tid]; int nn = redn[tid];
        int p = ((w * 2625 + nn) << 12) | (wb + nn);
        if (L > cntw) {
            int pp = ((w * 2625 + 125 + cntw) << 12) | 0xFFF;
            if (0.5f > v || (0.5f == v && pp < p)) { v = 0.5f; p = pp; }
        }
        size_t o = ((size_t)bq * 5 + w) * 25 + tid;
        ASTORE_F(&bvg[o], v); ASTORE_I(&bpg[o], p);
    }

    // ---- fused kce: last block of this bq computes the row loss ----
    // ALL global outputs above were issued by wave 0 -> one vmcnt(0)
    // in program order before the counter bump suffices. No fences.
    asm volatile("s_waitcnt vmcnt(0)" ::: "memory");
    if (tid == 0)
        lastf = (__hip_atomic_fetch_add(cntbq + bq, 1, __ATOMIC_RELAXED,
                                        __HIP_MEMORY_SCOPE_AGENT) == 4) ? 1 : 0;
    __syncthreads();
    if (!lastf) return;

    if (tid < 25) {
        float v = NEGINF; int p = 0x7fffffff;
#pragma unroll
        for (int w2 = 0; w2 < 5; ++w2) {
            size_t o = ((size_t)bq * 5 + w2) * 25 + tid;
            float v2 = ALOAD(&bvg[o]);
            int   p2 = ALOAD(&bpg[o]);
            if (v2 > v || (v2 == v && p2 < p)) { v = v2; p = p2; }
        }
        int pos = p & 0xFFF;
        int g = 0;
        if (pos != 0xFFF)
            g = (int)ALOAD(&amaxg[(size_t)bq * 3200 + pos]);
        qmask[tid] = (g == tid) ? 1.0f : 0.0f;
    }
    __syncthreads();
    if (tid < 5) {
        float s = 0.f;
#pragma unroll
        for (int mq = 0; mq < 25; ++mq) {
            size_t o = ((size_t)bq * 5 + tid) * 25 + mq;
            s += ALOAD(&bvg[o]) * qmask[mq];
        }
        lg[tid] = s;
    }
    __syncthreads();
    if (tid == 0) {
        int y = qy[bq];
        float mx = lg[0];
#pragma unroll
        for (int w2 = 1; w2 < 5; ++w2) mx = fmaxf(mx, lg[w2]);
        float se = 0.f;
#pragma unroll
        for (int w2 = 0; w2 < 5; ++w2) se += expf(lg[w2] - mx);
        float loss = -(lg[y] - mx - logf(se));
        atomicAdd(out, loss * (1.0f / 300.0f));
    }
}

// ============================================================
extern "C" void kernel_launch(void* const* d_in, const int* in_sizes, int n_in,
                              void* d_out, int out_size, void* d_ws, size_t ws_size,
                              hipStream_t stream)
{
    const float* sup = (const float*)d_in[0];
    const float* qry = (const float*)d_in[2];
    const int*   qy  = (const int*)d_in[3];
    const float* unl = (const float*)d_in[4];

    float* ws    = (float*)d_ws;
    float* unl_n = ws + OF_UNL;
    float* sup_n = ws + OF_SUP;
    float* supT  = ws + OF_SUPT;
    float* qt    = ws + OF_QT;
    unsigned long long* ukey = (unsigned long long*)(ws + OF_UKEY);
    unsigned long long* skey = (unsigned long long*)(ws + OF_SKEY);
    int*   cntbq = (int*)(ws + OF_CBQ);
    int*   cmp   = (int*)(ws + OF_CMP);
    int*   cntg  = (int*)(ws + OF_CNT);
    float* bvg   = ws + OF_BV;
    int*   bpg   = (int*)(ws + OF_BP);
    unsigned char* amaxg = (unsigned char*)(ws + OF_AMX);

    hipLaunchKernelGGL(knorm, dim3(200), dim3(256), 0, stream,
                       sup, qry, unl, ws, (float*)d_out);
    hipLaunchKernelGGL(kb, dim3(1600), dim3(256), 0, stream,
                       unl_n, supT, ukey, skey);
    hipLaunchKernelGGL(kcmp, dim3(20), dim3(256), 0, stream,
                       ukey, skey, cmp, cntg);
    hipLaunchKernelGGL(kc1, dim3(1500), dim3(256), 0, stream,
                       qt, sup_n, unl_n, cmp, cntg, bvg, bpg, amaxg,
                       cntbq, qy, (float*)d_out);
}